// Round 1
// baseline (520.253 us; speedup 1.0000x reference)
//
#include <hip/hip_runtime.h>

// GCN 2-layer forward on MI355X.
// out = A @ relu(A @ (x@W1) + b1) @ W2 + b2   (A = weighted edge aggregation)
// Strategy: matmul-first (F_out << F_in), CSR-by-dst built per call (no fp32 atomics
// in aggregation), support matrices stay L3-resident.

#define F0 512
#define F1 128
#define F2 40

// ---------------- CSR build ----------------
__global__ void hist_kernel(const int* __restrict__ dst, int* __restrict__ cnt, int E){
    int e = blockIdx.x*256 + threadIdx.x;
    if (e < E) atomicAdd(&cnt[dst[e]], 1);
}

__global__ void scan1_kernel(const int* __restrict__ cnt, int* __restrict__ offs,
                             int* __restrict__ bsum, int n){
    __shared__ int sd[256];
    int tid = threadIdx.x;
    int base = blockIdx.x*1024 + tid*4;
    int c0 = (base+0<n)?cnt[base+0]:0;
    int c1 = (base+1<n)?cnt[base+1]:0;
    int c2 = (base+2<n)?cnt[base+2]:0;
    int c3 = (base+3<n)?cnt[base+3]:0;
    int v1=c0, v2=c0+c1, v3=c0+c1+c2;
    int s = c0+c1+c2+c3;
    sd[tid]=s; __syncthreads();
    for (int off=1; off<256; off<<=1){
        int t = (tid>=off)? sd[tid-off] : 0;
        __syncthreads();
        sd[tid] += t;
        __syncthreads();
    }
    int excl = sd[tid] - s;
    if (base+0<n) offs[base+0]=excl;
    if (base+1<n) offs[base+1]=excl+v1;
    if (base+2<n) offs[base+2]=excl+v2;
    if (base+3<n) offs[base+3]=excl+v3;
    if (tid==255) bsum[blockIdx.x]=sd[255];
}

__global__ void scan2_kernel(int* bsum, int nb){  // nb must be <= 64 (50000/1024 = 49)
    __shared__ int sd[64];
    int tid=threadIdx.x;
    int s = (tid<nb)? bsum[tid]:0;
    sd[tid]=s; __syncthreads();
    for (int off=1; off<64; off<<=1){
        int t=(tid>=off)? sd[tid-off]:0;
        __syncthreads();
        sd[tid]+=t;
        __syncthreads();
    }
    if (tid<nb) bsum[tid]=sd[tid]-s;  // exclusive
}

__global__ void scan3_kernel(int* __restrict__ offs, int* __restrict__ cur,
                             const int* __restrict__ bsum, int n, int E){
    int i = blockIdx.x*256+threadIdx.x;
    if (i<n){ int o = offs[i]+bsum[i>>10]; offs[i]=o; cur[i]=o; }
    if (i==0) offs[n]=E;
}

__global__ void scatter_kernel(const int* __restrict__ src, const int* __restrict__ dst,
                               const float* __restrict__ w, int* __restrict__ cur,
                               int* __restrict__ ssrc, float* __restrict__ sw, int E){
    int e = blockIdx.x*256+threadIdx.x;
    if (e<E){
        int d = dst[e];
        int pos = atomicAdd(&cur[d],1);
        ssrc[pos]=src[e];
        sw[pos]=w[e];
    }
}

// ---------------- GEMM1: [M,512] @ [512,128] ----------------
__global__ __launch_bounds__(256) void gemm1_kernel(const float* __restrict__ X,
                                                    const float* __restrict__ W,
                                                    float* __restrict__ S, int M){
    __shared__ float sA[32][68];   // [k][m] transposed; stride 68 keeps float4 align
    __shared__ float sB[32][128];  // [k][n]
    int tid = threadIdx.x;
    int row0 = blockIdx.x * 64;
    int trow = tid >> 5;        // 0..7 -> 8 consecutive rows each
    int tcol = tid & 31;        // 0..31 -> 4 cols each
    float acc[8][4];
    #pragma unroll
    for (int i=0;i<8;i++)
        #pragma unroll
        for (int j=0;j<4;j++) acc[i][j]=0.f;

    for (int k0=0;k0<512;k0+=32){
        #pragma unroll
        for (int p=0;p<2;p++){
            int idx = tid + p*256;        // 0..511
            int r = idx >> 3;             // 0..63
            int kq = idx & 7;             // 0..7
            float4 xv = make_float4(0.f,0.f,0.f,0.f);
            int grow = row0 + r;
            if (grow < M) xv = *(const float4*)&X[(size_t)grow*F0 + k0 + kq*4];
            sA[kq*4+0][r] = xv.x;
            sA[kq*4+1][r] = xv.y;
            sA[kq*4+2][r] = xv.z;
            sA[kq*4+3][r] = xv.w;
        }
        #pragma unroll
        for (int p=0;p<4;p++){
            int idx = tid + p*256;   // 0..1023
            int kk = idx >> 5;       // 0..31
            int c4 = idx & 31;       // 0..31
            *(float4*)&sB[kk][c4*4] = *(const float4*)&W[(size_t)(k0+kk)*F1 + c4*4];
        }
        __syncthreads();
        #pragma unroll
        for (int kk=0;kk<32;kk++){
            float4 b  = *(const float4*)&sB[kk][tcol*4];
            float4 a0 = *(const float4*)&sA[kk][trow*8];
            float4 a1 = *(const float4*)&sA[kk][trow*8+4];
            float av[8] = {a0.x,a0.y,a0.z,a0.w,a1.x,a1.y,a1.z,a1.w};
            #pragma unroll
            for (int i=0;i<8;i++){
                acc[i][0] += av[i]*b.x;
                acc[i][1] += av[i]*b.y;
                acc[i][2] += av[i]*b.z;
                acc[i][3] += av[i]*b.w;
            }
        }
        __syncthreads();
    }
    #pragma unroll
    for (int i=0;i<8;i++){
        int grow = row0 + trow*8 + i;
        if (grow < M){
            float4 v = make_float4(acc[i][0],acc[i][1],acc[i][2],acc[i][3]);
            *(float4*)&S[(size_t)grow*F1 + tcol*4] = v;
        }
    }
}

// ---------------- agg1: h = relu(A@S1 + b1), F=128 ----------------
__global__ void agg1_kernel(const float* __restrict__ S, const int* __restrict__ offs,
                            const int* __restrict__ ssrc, const float* __restrict__ sw,
                            const float* __restrict__ b1, float* __restrict__ H, int n){
    int node = blockIdx.x;        // one block (128 threads) per node
    int f = threadIdx.x;
    int e0 = offs[node], e1 = offs[node+1];
    float acc = 0.f;
    for (int e=e0;e<e1;e++){
        int s = ssrc[e];
        float w = sw[e];
        acc += w * S[(size_t)s*F1 + f];
    }
    float v = acc + b1[f];
    H[(size_t)node*F1 + f] = v>0.f ? v : 0.f;
}

// ---------------- GEMM2: [M,128] @ [128,40] ----------------
__global__ __launch_bounds__(256) void gemm2_kernel(const float* __restrict__ H,
                                                    const float* __restrict__ W2,
                                                    float* __restrict__ S2, int M){
    __shared__ float sH[32][132];  // padded: bank = (4r+k)%32, conflict-free
    __shared__ float sW[128][40];
    int tid = threadIdx.x;
    int row0 = blockIdx.x*32;
    #pragma unroll
    for (int p=0;p<5;p++){
        int idx = tid + p*256;  // 0..1279 float4s
        int k = idx/10; int c4 = idx%10;
        *(float4*)&sW[k][c4*4] = *(const float4*)&W2[(size_t)k*F2 + c4*4];
    }
    #pragma unroll
    for (int p=0;p<4;p++){
        int idx = tid + p*256;  // 0..1023 float4s
        int r = idx>>5; int kq = idx&31;
        int grow = row0+r;
        float4 hv = make_float4(0.f,0.f,0.f,0.f);
        if (grow<M) hv = *(const float4*)&H[(size_t)grow*F1 + kq*4];
        *(float4*)&sH[r][kq*4] = hv;
    }
    __syncthreads();
    int r  = tid>>3;      // 0..31
    int cg = tid&7;       // 0..7 ; cols cg+8j, j=0..4
    float acc[5] = {0.f,0.f,0.f,0.f,0.f};
    for (int k=0;k<128;k++){
        float hv = sH[r][k];
        #pragma unroll
        for (int j=0;j<5;j++) acc[j] += hv * sW[k][cg + 8*j];
    }
    int grow = row0 + r;
    if (grow<M){
        #pragma unroll
        for (int j=0;j<5;j++) S2[(size_t)grow*F2 + cg + 8*j] = acc[j];
    }
}

// ---------------- agg2: out = A@S2 + b2, F=40 ----------------
__global__ void agg2_kernel(const float* __restrict__ S2, const int* __restrict__ offs,
                            const int* __restrict__ ssrc, const float* __restrict__ sw,
                            const float* __restrict__ b2, float* __restrict__ out, int n){
    int node = blockIdx.x*4 + (threadIdx.x>>6);  // one wave per node
    int f = threadIdx.x & 63;
    if (node >= n) return;
    int e0=offs[node], e1=offs[node+1];
    float acc=0.f;
    for (int e=e0;e<e1;e++){
        int s=ssrc[e]; float w=sw[e];
        if (f<F2) acc += w * S2[(size_t)s*F2+f];
    }
    if (f<F2) out[(size_t)node*F2+f] = acc + b2[f];
}

extern "C" void kernel_launch(void* const* d_in, const int* in_sizes, int n_in,
                              void* d_out, int out_size, void* d_ws, size_t ws_size,
                              hipStream_t stream){
    const float* x    = (const float*)d_in[0];
    const int*   esrc = (const int*)d_in[1];
    const int*   edst = (const int*)d_in[2];
    const float* ew   = (const float*)d_in[3];
    const float* W1   = (const float*)d_in[4];
    const float* b1   = (const float*)d_in[5];
    const float* W2   = (const float*)d_in[6];
    const float* b2   = (const float*)d_in[7];
    float* out = (float*)d_out;
    int N = in_sizes[0] / F0;   // 50000
    int E = in_sizes[1];        // 800000

    char* ws = (char*)d_ws;
    size_t off = 0;
    auto alloc = [&](size_t bytes)->void*{
        void* p = ws + off; off += (bytes + 255) & ~(size_t)255; return p;
    };
    float* S1   = (float*)alloc(sizeof(float)*(size_t)N*F1);  // 25.6 MB (S2 aliases)
    float* H    = (float*)alloc(sizeof(float)*(size_t)N*F1);  // 25.6 MB
    int*   offs = (int*)alloc(sizeof(int)*(size_t)(N+1));
    int*   cur  = (int*)alloc(sizeof(int)*(size_t)N);
    int*   ssrc = (int*)alloc(sizeof(int)*(size_t)E);
    float* sw   = (float*)alloc(sizeof(float)*(size_t)E);
    int*   bsum = (int*)alloc(sizeof(int)*64);
    float* S2 = S1;  // S1 dead after agg1

    // CSR build (ws is poisoned 0xAA each call -> must zero counts)
    hipMemsetAsync(cur, 0, sizeof(int)*(size_t)N, stream);
    hist_kernel<<<(E+255)/256,256,0,stream>>>(edst, cur, E);
    int nb = (N+1023)/1024;     // 49 <= 64
    scan1_kernel<<<nb,256,0,stream>>>(cur, offs, bsum, N);
    scan2_kernel<<<1,64,0,stream>>>(bsum, nb);
    scan3_kernel<<<(N+255)/256,256,0,stream>>>(offs, cur, bsum, N, E);
    scatter_kernel<<<(E+255)/256,256,0,stream>>>(esrc, edst, ew, cur, ssrc, sw, E);

    // layer 1
    gemm1_kernel<<<(N+63)/64,256,0,stream>>>(x, W1, S1, N);
    agg1_kernel<<<N,128,0,stream>>>(S1, offs, ssrc, sw, b1, H, N);
    // layer 2
    gemm2_kernel<<<(N+31)/32,256,0,stream>>>(H, W2, S2, N);
    agg2_kernel<<<(N+3)/4,256,0,stream>>>(S2, offs, ssrc, sw, b2, out, N);
}

// Round 3
// 402.210 us; speedup vs baseline: 1.2935x; 1.2935x over previous
//
#include <hip/hip_runtime.h>

// GCN 2-layer forward on MI355X (gfx950).
// out = A @ relu(A @ (x@W1) + b1) @ W2 + b2   (A = weighted edge aggregation)
// R3: split-bf16 MFMA GEMMs (fp32-accurate: a_hi*b_hi + a_lo*b_hi + a_hi*b_lo),
//     fp32 intermediates, fp64 aggregation accumulators -> bit-stable output
//     regardless of the atomic CSR scatter order.

#define F0 512
#define F1 128
#define F2 40

typedef short bf16x8 __attribute__((ext_vector_type(8)));
typedef float f32x4 __attribute__((ext_vector_type(4)));

static __device__ __forceinline__ unsigned short f2b(float f){
    union { float f; unsigned int u; } x; x.f = f;
    unsigned int u = x.u;
    unsigned int r = (u + 0x7fffu + ((u >> 16) & 1u)) >> 16;  // RNE
    return (unsigned short)r;
}
static __device__ __forceinline__ float b2f(unsigned short h){
    union { unsigned int u; float f; } x; x.u = ((unsigned int)h) << 16; return x.f;
}

// split a into hi+lo bf16 pair: a = b2f(hi) + b2f(lo) + O(2^-17 rel)
static __device__ __forceinline__ void split1(float a, unsigned short& hi, unsigned short& lo){
    hi = f2b(a);
    lo = f2b(a - b2f(hi));
}
static __device__ __forceinline__ void split8(const float* p, bf16x8& hi, bf16x8& lo){
    float4 v0 = *(const float4*)p;
    float4 v1 = *(const float4*)(p+4);
    float a[8] = {v0.x,v0.y,v0.z,v0.w,v1.x,v1.y,v1.z,v1.w};
    #pragma unroll
    for (int j=0;j<8;j++){
        unsigned short h, l; split1(a[j], h, l);
        hi[j] = (short)h; lo[j] = (short)l;
    }
}

// ---------------- CSR build ----------------
__global__ void hist_kernel(const int* __restrict__ dst, int* __restrict__ cnt, int E){
    int e = blockIdx.x*256 + threadIdx.x;
    if (e < E) atomicAdd(&cnt[dst[e]], 1);
}

__global__ void scan1_kernel(const int* __restrict__ cnt, int* __restrict__ offs,
                             int* __restrict__ bsum, int n){
    __shared__ int sd[256];
    int tid = threadIdx.x;
    int base = blockIdx.x*1024 + tid*4;
    int c0 = (base+0<n)?cnt[base+0]:0;
    int c1 = (base+1<n)?cnt[base+1]:0;
    int c2 = (base+2<n)?cnt[base+2]:0;
    int c3 = (base+3<n)?cnt[base+3]:0;
    int v1=c0, v2=c0+c1, v3=c0+c1+c2;
    int s = c0+c1+c2+c3;
    sd[tid]=s; __syncthreads();
    for (int off=1; off<256; off<<=1){
        int t = (tid>=off)? sd[tid-off] : 0;
        __syncthreads();
        sd[tid] += t;
        __syncthreads();
    }
    int excl = sd[tid] - s;
    if (base+0<n) offs[base+0]=excl;
    if (base+1<n) offs[base+1]=excl+v1;
    if (base+2<n) offs[base+2]=excl+v2;
    if (base+3<n) offs[base+3]=excl+v3;
    if (tid==255) bsum[blockIdx.x]=sd[255];
}

__global__ void scan2_kernel(int* bsum, int nb){  // nb <= 64
    __shared__ int sd[64];
    int tid=threadIdx.x;
    int s = (tid<nb)? bsum[tid]:0;
    sd[tid]=s; __syncthreads();
    for (int off=1; off<64; off<<=1){
        int t=(tid>=off)? sd[tid-off]:0;
        __syncthreads();
        sd[tid]+=t;
        __syncthreads();
    }
    if (tid<nb) bsum[tid]=sd[tid]-s;  // exclusive
}

__global__ void scan3_kernel(int* __restrict__ offs, int* __restrict__ cur,
                             const int* __restrict__ bsum, int n, int E){
    int i = blockIdx.x*256+threadIdx.x;
    if (i<n){ int o = offs[i]+bsum[i>>10]; offs[i]=o; cur[i]=o; }
    if (i==0) offs[n]=E;
}

__global__ void scatter_kernel(const int* __restrict__ src, const int* __restrict__ dst,
                               const float* __restrict__ w, int* __restrict__ cur,
                               int* __restrict__ ssrc, float* __restrict__ sw, int E){
    int e = blockIdx.x*256+threadIdx.x;
    if (e<E){
        int d = dst[e];
        int pos = atomicAdd(&cur[d],1);
        ssrc[pos]=src[e];
        sw[pos]=w[e];
    }
}

// ---------------- weight prep (transpose + hi/lo split) ----------------
__global__ void prep_w1(const float* __restrict__ W1,
                        unsigned short* __restrict__ W1th, unsigned short* __restrict__ W1tl){
    // W1 [512][128] fp32 -> W1t{h,l} [128][512] bf16
    int idx = blockIdx.x*256 + threadIdx.x;   // 65536
    int k = idx >> 7, n = idx & 127;
    unsigned short h, l; split1(W1[idx], h, l);
    W1th[(size_t)n*F0 + k] = h;
    W1tl[(size_t)n*F0 + k] = l;
}
__global__ void prep_w2(const float* __restrict__ W2,
                        unsigned short* __restrict__ W2th, unsigned short* __restrict__ W2tl){
    // W2 [128][40] fp32 -> W2t{h,l} [48][128] bf16 (rows 40..47 zero)
    int idx = blockIdx.x*256 + threadIdx.x;   // 6144
    int n = idx >> 7, k = idx & 127;
    float v = (n < F2) ? W2[(size_t)k*F2 + n] : 0.f;
    unsigned short h, l; split1(v, h, l);
    W2th[idx] = h; W2tl[idx] = l;
}

// ---------------- GEMM1: X[M,512]fp32 @ W1 -> S1 fp32 [M,128] (split-bf16) ----
__global__ __launch_bounds__(256) void gemm1_mfma(const float* __restrict__ X,
                                                  const unsigned short* __restrict__ W1th,
                                                  const unsigned short* __restrict__ W1tl,
                                                  float* __restrict__ S1, int M){
    __shared__ unsigned short sBh[128][72];  // stride 72: 2-way bank alias only (free)
    __shared__ unsigned short sBl[128][72];
    int tid = threadIdx.x;
    int wave = tid >> 6, lane = tid & 63;
    int quad = lane >> 4, l16 = lane & 15;
    int row0 = blockIdx.x * 64;
    int myrow = row0 + wave*16 + l16;
    int arow = min(myrow, M-1);
    const float* xrow = X + (size_t)arow * F0;

    f32x4 acc[8];
    #pragma unroll
    for (int c=0;c<8;c++) acc[c] = (f32x4){0.f,0.f,0.f,0.f};

    int sn = tid >> 1, shalf = tid & 1;   // each thread stages 64B of one row (hi+lo)
    for (int k0 = 0; k0 < F0; k0 += 64){
        {
            const unsigned short* srch = W1th + (size_t)sn*F0 + k0 + shalf*32;
            const unsigned short* srcl = W1tl + (size_t)sn*F0 + k0 + shalf*32;
            unsigned short* dsth = &sBh[sn][shalf*32];
            unsigned short* dstl = &sBl[sn][shalf*32];
            *(float4*)(dsth+ 0) = *(const float4*)(srch+ 0);
            *(float4*)(dsth+ 8) = *(const float4*)(srch+ 8);
            *(float4*)(dsth+16) = *(const float4*)(srch+16);
            *(float4*)(dsth+24) = *(const float4*)(srch+24);
            *(float4*)(dstl+ 0) = *(const float4*)(srcl+ 0);
            *(float4*)(dstl+ 8) = *(const float4*)(srcl+ 8);
            *(float4*)(dstl+16) = *(const float4*)(srcl+16);
            *(float4*)(dstl+24) = *(const float4*)(srcl+24);
        }
        __syncthreads();
        bf16x8 ah0, al0, ah1, al1;
        split8(xrow + k0 + quad*8, ah0, al0);
        split8(xrow + k0 + 32 + quad*8, ah1, al1);
        #pragma unroll
        for (int c=0;c<8;c++){
            bf16x8 bh0 = *(bf16x8*)&sBh[c*16 + l16][quad*8];
            bf16x8 bl0 = *(bf16x8*)&sBl[c*16 + l16][quad*8];
            bf16x8 bh1 = *(bf16x8*)&sBh[c*16 + l16][32 + quad*8];
            bf16x8 bl1 = *(bf16x8*)&sBl[c*16 + l16][32 + quad*8];
            acc[c] = __builtin_amdgcn_mfma_f32_16x16x32_bf16(ah0, bh0, acc[c], 0, 0, 0);
            acc[c] = __builtin_amdgcn_mfma_f32_16x16x32_bf16(al0, bh0, acc[c], 0, 0, 0);
            acc[c] = __builtin_amdgcn_mfma_f32_16x16x32_bf16(ah0, bl0, acc[c], 0, 0, 0);
            acc[c] = __builtin_amdgcn_mfma_f32_16x16x32_bf16(ah1, bh1, acc[c], 0, 0, 0);
            acc[c] = __builtin_amdgcn_mfma_f32_16x16x32_bf16(al1, bh1, acc[c], 0, 0, 0);
            acc[c] = __builtin_amdgcn_mfma_f32_16x16x32_bf16(ah1, bl1, acc[c], 0, 0, 0);
        }
        __syncthreads();
    }
    // C/D: col = c*16 + l16, row = quad*4 + r
    #pragma unroll
    for (int c=0;c<8;c++){
        #pragma unroll
        for (int r=0;r<4;r++){
            int grow = row0 + wave*16 + quad*4 + r;
            if (grow < M) S1[(size_t)grow*F1 + c*16 + l16] = acc[c][r];
        }
    }
}

// ---------------- agg1: H = relu(A@S1 + b1) fp32, F=128, fp64 accum ----------
__global__ void agg1_kernel(const float2* __restrict__ S1, const int* __restrict__ offs,
                            const int* __restrict__ ssrc, const float* __restrict__ sw,
                            const float* __restrict__ b1, float2* __restrict__ H, int n){
    int node = blockIdx.x*4 + (threadIdx.x >> 6);   // one wave per node
    int lane = threadIdx.x & 63;
    if (node >= n) return;
    int e0 = offs[node], e1 = offs[node+1];
    double ax = 0.0, ay = 0.0;
    int e = e0;
    for (; e+4 <= e1; e += 4){
        int s0=ssrc[e], s1=ssrc[e+1], s2=ssrc[e+2], s3=ssrc[e+3];
        double w0=sw[e], w1=sw[e+1], w2=sw[e+2], w3=sw[e+3];
        float2 v0 = S1[(size_t)s0*64 + lane];
        float2 v1 = S1[(size_t)s1*64 + lane];
        float2 v2 = S1[(size_t)s2*64 + lane];
        float2 v3 = S1[(size_t)s3*64 + lane];
        ax += w0*(double)v0.x + w1*(double)v1.x + w2*(double)v2.x + w3*(double)v3.x;
        ay += w0*(double)v0.y + w1*(double)v1.y + w2*(double)v2.y + w3*(double)v3.y;
    }
    for (; e < e1; e++){
        int s = ssrc[e]; double w = sw[e];
        float2 v = S1[(size_t)s*64 + lane];
        ax += w*(double)v.x; ay += w*(double)v.y;
    }
    float2 bb = ((const float2*)b1)[lane];
    float vx = (float)(ax + (double)bb.x);
    float vy = (float)(ay + (double)bb.y);
    float2 o; o.x = vx > 0.f ? vx : 0.f; o.y = vy > 0.f ? vy : 0.f;
    H[(size_t)node*64 + lane] = o;
}

// ---------------- GEMM2: H fp32 [M,128] @ W2 -> S2 fp32 [M,40] (split-bf16) ---
__global__ __launch_bounds__(256) void gemm2_mfma(const float* __restrict__ H,
                                                  const unsigned short* __restrict__ W2th,
                                                  const unsigned short* __restrict__ W2tl,
                                                  float* __restrict__ S2, int M){
    __shared__ unsigned short sBh[48][136];
    __shared__ unsigned short sBl[48][136];
    int tid = threadIdx.x;
    int wave = tid >> 6, lane = tid & 63;
    int quad = lane >> 4, l16 = lane & 15;
    for (int i = tid; i < 48*16; i += 256){
        int nn = i >> 4, p = i & 15;
        *(float4*)&sBh[nn][p*8] = *(const float4*)&W2th[(size_t)nn*F1 + p*8];
        *(float4*)&sBl[nn][p*8] = *(const float4*)&W2tl[(size_t)nn*F1 + p*8];
    }
    __syncthreads();
    int row0 = blockIdx.x * 64;
    int myrow = row0 + wave*16 + l16;
    int arow = min(myrow, M-1);
    const float* hrow = H + (size_t)arow * F1;
    f32x4 acc[3];
    #pragma unroll
    for (int c=0;c<3;c++) acc[c] = (f32x4){0.f,0.f,0.f,0.f};
    #pragma unroll
    for (int ks=0; ks<4; ks++){
        bf16x8 ah, al;
        split8(hrow + ks*32 + quad*8, ah, al);
        #pragma unroll
        for (int c=0;c<3;c++){
            bf16x8 bh = *(bf16x8*)&sBh[c*16 + l16][ks*32 + quad*8];
            bf16x8 bl = *(bf16x8*)&sBl[c*16 + l16][ks*32 + quad*8];
            acc[c] = __builtin_amdgcn_mfma_f32_16x16x32_bf16(ah, bh, acc[c], 0, 0, 0);
            acc[c] = __builtin_amdgcn_mfma_f32_16x16x32_bf16(al, bh, acc[c], 0, 0, 0);
            acc[c] = __builtin_amdgcn_mfma_f32_16x16x32_bf16(ah, bl, acc[c], 0, 0, 0);
        }
    }
    #pragma unroll
    for (int c=0;c<3;c++){
        #pragma unroll
        for (int r=0;r<4;r++){
            int grow = row0 + wave*16 + quad*4 + r;
            int col = c*16 + l16;
            if (grow < M && col < F2) S2[(size_t)grow*F2 + col] = acc[c][r];
        }
    }
}

// ---------------- agg2: out = A@S2 + b2, F=40, fp64 accum --------------------
__global__ void agg2_kernel(const float* __restrict__ S2, const int* __restrict__ offs,
                            const int* __restrict__ ssrc, const float* __restrict__ sw,
                            const float* __restrict__ b2, float* __restrict__ out, int n){
    int node = blockIdx.x*4 + (threadIdx.x >> 6);  // one wave per node
    int f = threadIdx.x & 63;
    if (node >= n) return;
    int e0 = offs[node], e1 = offs[node+1];
    bool act = f < F2;
    double acc = 0.0;
    int e = e0;
    for (; e+4 <= e1; e += 4){
        int s0=ssrc[e], s1=ssrc[e+1], s2=ssrc[e+2], s3=ssrc[e+3];
        double w0=sw[e], w1=sw[e+1], w2=sw[e+2], w3=sw[e+3];
        if (act){
            acc += w0*(double)S2[(size_t)s0*F2+f] + w1*(double)S2[(size_t)s1*F2+f]
                 + w2*(double)S2[(size_t)s2*F2+f] + w3*(double)S2[(size_t)s3*F2+f];
        }
    }
    for (; e < e1; e++){
        if (act) acc += (double)sw[e]*(double)S2[(size_t)ssrc[e]*F2+f];
    }
    if (act) out[(size_t)node*F2+f] = (float)(acc + (double)b2[f]);
}

extern "C" void kernel_launch(void* const* d_in, const int* in_sizes, int n_in,
                              void* d_out, int out_size, void* d_ws, size_t ws_size,
                              hipStream_t stream){
    const float* x    = (const float*)d_in[0];
    const int*   esrc = (const int*)d_in[1];
    const int*   edst = (const int*)d_in[2];
    const float* ew   = (const float*)d_in[3];
    const float* W1   = (const float*)d_in[4];
    const float* b1   = (const float*)d_in[5];
    const float* W2   = (const float*)d_in[6];
    const float* b2   = (const float*)d_in[7];
    float* out = (float*)d_out;
    int N = in_sizes[0] / F0;   // 50000
    int E = in_sizes[1];        // 800000

    char* ws = (char*)d_ws;
    size_t off = 0;
    auto alloc = [&](size_t bytes)->void*{
        void* p = ws + off; off += (bytes + 255) & ~(size_t)255; return p;
    };
    float* S1 = (float*)alloc(sizeof(float)*(size_t)N*F1);   // 25.6 MB (S2 aliases)
    float* H  = (float*)alloc(sizeof(float)*(size_t)N*F1);   // 25.6 MB
    unsigned short* W1th = (unsigned short*)alloc(sizeof(unsigned short)*F1*F0);
    unsigned short* W1tl = (unsigned short*)alloc(sizeof(unsigned short)*F1*F0);
    unsigned short* W2th = (unsigned short*)alloc(sizeof(unsigned short)*48*F1);
    unsigned short* W2tl = (unsigned short*)alloc(sizeof(unsigned short)*48*F1);
    int*   offs = (int*)alloc(sizeof(int)*(size_t)(N+1));
    int*   cur  = (int*)alloc(sizeof(int)*(size_t)N);
    int*   ssrc = (int*)alloc(sizeof(int)*(size_t)E);
    float* sw   = (float*)alloc(sizeof(float)*(size_t)E);
    int*   bsum = (int*)alloc(sizeof(int)*64);
    float* S2 = S1;  // S1 dead after agg1

    // CSR build (ws re-poisoned each call -> zero counts first)
    hipMemsetAsync(cur, 0, sizeof(int)*(size_t)N, stream);
    hist_kernel<<<(E+255)/256,256,0,stream>>>(edst, cur, E);
    int nb = (N+1023)/1024;     // 49 <= 64
    scan1_kernel<<<nb,256,0,stream>>>(cur, offs, bsum, N);
    scan2_kernel<<<1,64,0,stream>>>(bsum, nb);
    scan3_kernel<<<(N+255)/256,256,0,stream>>>(offs, cur, bsum, N, E);
    scatter_kernel<<<(E+255)/256,256,0,stream>>>(esrc, edst, ew, cur, ssrc, sw, E);

    // weight prep
    prep_w1<<<(F0*F1)/256,256,0,stream>>>(W1, W1th, W1tl);
    prep_w2<<<(48*F1)/256,256,0,stream>>>(W2, W2th, W2tl);

    // layer 1
    gemm1_mfma<<<(N+63)/64,256,0,stream>>>(x, W1th, W1tl, S1, N);
    agg1_kernel<<<(N+3)/4,256,0,stream>>>((const float2*)S1, offs, ssrc, sw, b1, (float2*)H, N);
    // layer 2
    gemm2_mfma<<<(N+63)/64,256,0,stream>>>(H, W2th, W2tl, S2, N);
    agg2_kernel<<<(N+3)/4,256,0,stream>>>(S2, offs, ssrc, sw, b2, out, N);
}

// Round 4
// 367.277 us; speedup vs baseline: 1.4165x; 1.0951x over previous
//
#include <hip/hip_runtime.h>

// GCN 2-layer forward on MI355X (gfx950).
// out = A @ relu(A @ (x@W1) + b1) @ W2 + b2   (A = weighted edge aggregation)
// R4: pipelined gemm1 (reg-prefetch A + B), bf16 intermediates (S1,H,S2) with
//     fp64 aggregation accumulators (bit-deterministic under CSR reorder),
//     int2-packed edge records.

#define F0 512
#define F1 128
#define F2 40
#define F2P 48   // padded S2 row (bf16)

typedef short bf16x8 __attribute__((ext_vector_type(8)));
typedef float f32x4 __attribute__((ext_vector_type(4)));

static __device__ __forceinline__ unsigned short f2b(float f){
    union { float f; unsigned int u; } x; x.f = f;
    unsigned int u = x.u;
    unsigned int r = (u + 0x7fffu + ((u >> 16) & 1u)) >> 16;  // RNE
    return (unsigned short)r;
}
static __device__ __forceinline__ float b2f(unsigned short h){
    union { unsigned int u; float f; } x; x.u = ((unsigned int)h) << 16; return x.f;
}
static __device__ __forceinline__ void split1(float a, unsigned short& hi, unsigned short& lo){
    hi = f2b(a);
    lo = f2b(a - b2f(hi));
}
static __device__ __forceinline__ void split8(float4 v0, float4 v1, bf16x8& hi, bf16x8& lo){
    float a[8] = {v0.x,v0.y,v0.z,v0.w,v1.x,v1.y,v1.z,v1.w};
    #pragma unroll
    for (int j=0;j<8;j++){
        unsigned short h, l; split1(a[j], h, l);
        hi[j] = (short)h; lo[j] = (short)l;
    }
}

// ---------------- CSR build ----------------
__global__ void hist_kernel(const int* __restrict__ dst, int* __restrict__ cnt, int E){
    int e = blockIdx.x*256 + threadIdx.x;
    if (e < E) atomicAdd(&cnt[dst[e]], 1);
}

__global__ void scan1_kernel(const int* __restrict__ cnt, int* __restrict__ offs,
                             int* __restrict__ bsum, int n){
    __shared__ int sd[256];
    int tid = threadIdx.x;
    int base = blockIdx.x*1024 + tid*4;
    int c0 = (base+0<n)?cnt[base+0]:0;
    int c1 = (base+1<n)?cnt[base+1]:0;
    int c2 = (base+2<n)?cnt[base+2]:0;
    int c3 = (base+3<n)?cnt[base+3]:0;
    int v1=c0, v2=c0+c1, v3=c0+c1+c2;
    int s = c0+c1+c2+c3;
    sd[tid]=s; __syncthreads();
    for (int off=1; off<256; off<<=1){
        int t = (tid>=off)? sd[tid-off] : 0;
        __syncthreads();
        sd[tid] += t;
        __syncthreads();
    }
    int excl = sd[tid] - s;
    if (base+0<n) offs[base+0]=excl;
    if (base+1<n) offs[base+1]=excl+v1;
    if (base+2<n) offs[base+2]=excl+v2;
    if (base+3<n) offs[base+3]=excl+v3;
    if (tid==255) bsum[blockIdx.x]=sd[255];
}

__global__ void scan2_kernel(int* bsum, int nb){  // nb <= 64
    __shared__ int sd[64];
    int tid=threadIdx.x;
    int s = (tid<nb)? bsum[tid]:0;
    sd[tid]=s; __syncthreads();
    for (int off=1; off<64; off<<=1){
        int t=(tid>=off)? sd[tid-off]:0;
        __syncthreads();
        sd[tid]+=t;
        __syncthreads();
    }
    if (tid<nb) bsum[tid]=sd[tid]-s;  // exclusive
}

__global__ void scan3_kernel(int* __restrict__ offs, int* __restrict__ cur,
                             const int* __restrict__ bsum, int n, int E){
    int i = blockIdx.x*256+threadIdx.x;
    if (i<n){ int o = offs[i]+bsum[i>>10]; offs[i]=o; cur[i]=o; }
    if (i==0) offs[n]=E;
}

__global__ void scatter_kernel(const int* __restrict__ src, const int* __restrict__ dst,
                               const float* __restrict__ w, int* __restrict__ cur,
                               int2* __restrict__ edges, int E){
    int e = blockIdx.x*256+threadIdx.x;
    if (e<E){
        int d = dst[e];
        int pos = atomicAdd(&cur[d],1);
        int2 rec; rec.x = src[e]; rec.y = __float_as_int(w[e]);
        edges[pos] = rec;
    }
}

// ---------------- weight prep (transpose + hi/lo split) ----------------
__global__ void prep_w1(const float* __restrict__ W1,
                        unsigned short* __restrict__ W1th, unsigned short* __restrict__ W1tl){
    int idx = blockIdx.x*256 + threadIdx.x;   // 65536
    int k = idx >> 7, n = idx & 127;
    unsigned short h, l; split1(W1[idx], h, l);
    W1th[(size_t)n*F0 + k] = h;
    W1tl[(size_t)n*F0 + k] = l;
}
__global__ void prep_w2(const float* __restrict__ W2,
                        unsigned short* __restrict__ W2th, unsigned short* __restrict__ W2tl){
    int idx = blockIdx.x*256 + threadIdx.x;   // 6144
    int n = idx >> 7, k = idx & 127;
    float v = (n < F2) ? W2[(size_t)k*F2 + n] : 0.f;
    unsigned short h, l; split1(v, h, l);
    W2th[idx] = h; W2tl[idx] = l;
}

// ---- GEMM1: X[M,512]fp32 @ W1 -> S1 bf16 [M,128] (split-bf16, pipelined) ----
__global__ __launch_bounds__(256) void gemm1_mfma(const float* __restrict__ X,
                                                  const unsigned short* __restrict__ W1th,
                                                  const unsigned short* __restrict__ W1tl,
                                                  unsigned short* __restrict__ S1, int M){
    __shared__ unsigned short sBh[128][72];  // 144B row stride -> 2-way bank alias (free)
    __shared__ unsigned short sBl[128][72];
    int tid = threadIdx.x;
    int wave = tid >> 6, lane = tid & 63;
    int quad = lane >> 4, l16 = lane & 15;
    int row0 = blockIdx.x * 64;
    int myrow = row0 + wave*16 + l16;
    int arow = min(myrow, M-1);
    const float* xrow = X + (size_t)arow * F0;

    int sn = tid >> 1, shalf = tid & 1;  // B staging: 32 shorts of row sn per thread
    const unsigned short* bsrch = W1th + (size_t)sn*F0 + shalf*32;
    const unsigned short* bsrcl = W1tl + (size_t)sn*F0 + shalf*32;
    unsigned short* bdsth = &sBh[sn][shalf*32];
    unsigned short* bdstl = &sBl[sn][shalf*32];

    f32x4 acc[8];
    #pragma unroll
    for (int c=0;c<8;c++) acc[c] = (f32x4){0.f,0.f,0.f,0.f};

    // ---- prologue: load k0=0 tile (A->regs, B->regs->LDS) ----
    float4 a0 = *(const float4*)(xrow + quad*8);
    float4 a1 = *(const float4*)(xrow + quad*8 + 4);
    float4 a2 = *(const float4*)(xrow + 32 + quad*8);
    float4 a3 = *(const float4*)(xrow + 32 + quad*8 + 4);
    {
        float4 bh0 = *(const float4*)(bsrch+ 0), bh1 = *(const float4*)(bsrch+ 8);
        float4 bh2 = *(const float4*)(bsrch+16), bh3 = *(const float4*)(bsrch+24);
        float4 bl0 = *(const float4*)(bsrcl+ 0), bl1 = *(const float4*)(bsrcl+ 8);
        float4 bl2 = *(const float4*)(bsrcl+16), bl3 = *(const float4*)(bsrcl+24);
        *(float4*)(bdsth+ 0)=bh0; *(float4*)(bdsth+ 8)=bh1;
        *(float4*)(bdsth+16)=bh2; *(float4*)(bdsth+24)=bh3;
        *(float4*)(bdstl+ 0)=bl0; *(float4*)(bdstl+ 8)=bl1;
        *(float4*)(bdstl+16)=bl2; *(float4*)(bdstl+24)=bl3;
    }
    __syncthreads();

    for (int k0 = 0; k0 < F0; k0 += 64){
        bool more = (k0 + 64) < F0;
        // ---- prefetch next tile into registers (overlaps MFMA below) ----
        float4 na0, na1, na2, na3;
        float4 nbh0, nbh1, nbh2, nbh3, nbl0, nbl1, nbl2, nbl3;
        if (more){
            const float* nx = xrow + k0 + 64;
            na0 = *(const float4*)(nx + quad*8);
            na1 = *(const float4*)(nx + quad*8 + 4);
            na2 = *(const float4*)(nx + 32 + quad*8);
            na3 = *(const float4*)(nx + 32 + quad*8 + 4);
            const unsigned short* ph = bsrch + k0 + 64;
            const unsigned short* pl = bsrcl + k0 + 64;
            nbh0 = *(const float4*)(ph+ 0); nbh1 = *(const float4*)(ph+ 8);
            nbh2 = *(const float4*)(ph+16); nbh3 = *(const float4*)(ph+24);
            nbl0 = *(const float4*)(pl+ 0); nbl1 = *(const float4*)(pl+ 8);
            nbl2 = *(const float4*)(pl+16); nbl3 = *(const float4*)(pl+24);
        }
        // ---- compute on current tile ----
        bf16x8 ah0, al0, ah1, al1;
        split8(a0, a1, ah0, al0);
        split8(a2, a3, ah1, al1);
        #pragma unroll
        for (int c=0;c<8;c++){
            bf16x8 bh0 = *(bf16x8*)&sBh[c*16 + l16][quad*8];
            bf16x8 bl0 = *(bf16x8*)&sBl[c*16 + l16][quad*8];
            bf16x8 bh1 = *(bf16x8*)&sBh[c*16 + l16][32 + quad*8];
            bf16x8 bl1 = *(bf16x8*)&sBl[c*16 + l16][32 + quad*8];
            acc[c] = __builtin_amdgcn_mfma_f32_16x16x32_bf16(ah0, bh0, acc[c], 0, 0, 0);
            acc[c] = __builtin_amdgcn_mfma_f32_16x16x32_bf16(al0, bh0, acc[c], 0, 0, 0);
            acc[c] = __builtin_amdgcn_mfma_f32_16x16x32_bf16(ah0, bl0, acc[c], 0, 0, 0);
            acc[c] = __builtin_amdgcn_mfma_f32_16x16x32_bf16(ah1, bh1, acc[c], 0, 0, 0);
            acc[c] = __builtin_amdgcn_mfma_f32_16x16x32_bf16(al1, bh1, acc[c], 0, 0, 0);
            acc[c] = __builtin_amdgcn_mfma_f32_16x16x32_bf16(ah1, bl1, acc[c], 0, 0, 0);
        }
        if (more){
            __syncthreads();   // all waves done reading LDS
            *(float4*)(bdsth+ 0)=nbh0; *(float4*)(bdsth+ 8)=nbh1;
            *(float4*)(bdsth+16)=nbh2; *(float4*)(bdsth+24)=nbh3;
            *(float4*)(bdstl+ 0)=nbl0; *(float4*)(bdstl+ 8)=nbl1;
            *(float4*)(bdstl+16)=nbl2; *(float4*)(bdstl+24)=nbl3;
            __syncthreads();
            a0 = na0; a1 = na1; a2 = na2; a3 = na3;
        }
    }
    // C/D: col = c*16 + l16, row = quad*4 + r
    #pragma unroll
    for (int c=0;c<8;c++){
        #pragma unroll
        for (int r=0;r<4;r++){
            int grow = row0 + wave*16 + quad*4 + r;
            if (grow < M) S1[(size_t)grow*F1 + c*16 + l16] = f2b(acc[c][r]);
        }
    }
}

// ---- agg1: H = relu(A@S1 + b1) bf16, F=128, fp64 accum ----
__global__ void agg1_kernel(const ushort2* __restrict__ S1, const int* __restrict__ offs,
                            const int2* __restrict__ edges,
                            const float* __restrict__ b1, ushort2* __restrict__ H, int n){
    int node = blockIdx.x*4 + (threadIdx.x >> 6);   // one wave per node
    int lane = threadIdx.x & 63;
    if (node >= n) return;
    int e0 = offs[node], e1 = offs[node+1];
    double ax = 0.0, ay = 0.0;
    int e = e0;
    for (; e+8 <= e1; e += 8){
        int2 p0=edges[e],   p1=edges[e+1], p2=edges[e+2], p3=edges[e+3];
        int2 p4=edges[e+4], p5=edges[e+5], p6=edges[e+6], p7=edges[e+7];
        ushort2 v0 = S1[(size_t)p0.x*64 + lane];
        ushort2 v1 = S1[(size_t)p1.x*64 + lane];
        ushort2 v2 = S1[(size_t)p2.x*64 + lane];
        ushort2 v3 = S1[(size_t)p3.x*64 + lane];
        ushort2 v4 = S1[(size_t)p4.x*64 + lane];
        ushort2 v5 = S1[(size_t)p5.x*64 + lane];
        ushort2 v6 = S1[(size_t)p6.x*64 + lane];
        ushort2 v7 = S1[(size_t)p7.x*64 + lane];
        double w0=__int_as_float(p0.y), w1=__int_as_float(p1.y);
        double w2=__int_as_float(p2.y), w3=__int_as_float(p3.y);
        double w4=__int_as_float(p4.y), w5=__int_as_float(p5.y);
        double w6=__int_as_float(p6.y), w7=__int_as_float(p7.y);
        ax += w0*b2f(v0.x)+w1*b2f(v1.x)+w2*b2f(v2.x)+w3*b2f(v3.x)
            + w4*b2f(v4.x)+w5*b2f(v5.x)+w6*b2f(v6.x)+w7*b2f(v7.x);
        ay += w0*b2f(v0.y)+w1*b2f(v1.y)+w2*b2f(v2.y)+w3*b2f(v3.y)
            + w4*b2f(v4.y)+w5*b2f(v5.y)+w6*b2f(v6.y)+w7*b2f(v7.y);
    }
    for (; e < e1; e++){
        int2 p = edges[e];
        double w = __int_as_float(p.y);
        ushort2 v = S1[(size_t)p.x*64 + lane];
        ax += w*b2f(v.x); ay += w*b2f(v.y);
    }
    float2 bb = ((const float2*)b1)[lane];
    float vx = (float)(ax + (double)bb.x);
    float vy = (float)(ay + (double)bb.y);
    ushort2 o;
    o.x = f2b(vx > 0.f ? vx : 0.f);
    o.y = f2b(vy > 0.f ? vy : 0.f);
    H[(size_t)node*64 + lane] = o;
}

// ---- GEMM2: H bf16 [M,128] @ W2 -> S2 bf16 [M,48] (B split hi/lo) ----
__global__ __launch_bounds__(256) void gemm2_mfma(const unsigned short* __restrict__ H,
                                                  const unsigned short* __restrict__ W2th,
                                                  const unsigned short* __restrict__ W2tl,
                                                  unsigned short* __restrict__ S2, int M){
    __shared__ unsigned short sBh[48][136];
    __shared__ unsigned short sBl[48][136];
    int tid = threadIdx.x;
    int wave = tid >> 6, lane = tid & 63;
    int quad = lane >> 4, l16 = lane & 15;
    for (int i = tid; i < 48*16; i += 256){
        int nn = i >> 4, p = i & 15;
        *(float4*)&sBh[nn][p*8] = *(const float4*)&W2th[(size_t)nn*F1 + p*8];
        *(float4*)&sBl[nn][p*8] = *(const float4*)&W2tl[(size_t)nn*F1 + p*8];
    }
    int row0 = blockIdx.x * 64;
    int myrow = row0 + wave*16 + l16;
    int arow = min(myrow, M-1);
    const unsigned short* hrow = H + (size_t)arow * F1;
    bf16x8 a[4];
    #pragma unroll
    for (int ks=0; ks<4; ks++) a[ks] = *(const bf16x8*)(hrow + ks*32 + quad*8);
    __syncthreads();
    f32x4 acc[3];
    #pragma unroll
    for (int c=0;c<3;c++) acc[c] = (f32x4){0.f,0.f,0.f,0.f};
    #pragma unroll
    for (int ks=0; ks<4; ks++){
        #pragma unroll
        for (int c=0;c<3;c++){
            bf16x8 bh = *(bf16x8*)&sBh[c*16 + l16][ks*32 + quad*8];
            bf16x8 bl = *(bf16x8*)&sBl[c*16 + l16][ks*32 + quad*8];
            acc[c] = __builtin_amdgcn_mfma_f32_16x16x32_bf16(a[ks], bh, acc[c], 0, 0, 0);
            acc[c] = __builtin_amdgcn_mfma_f32_16x16x32_bf16(a[ks], bl, acc[c], 0, 0, 0);
        }
    }
    #pragma unroll
    for (int c=0;c<3;c++){
        #pragma unroll
        for (int r=0;r<4;r++){
            int grow = row0 + wave*16 + quad*4 + r;
            if (grow < M) S2[(size_t)grow*F2P + c*16 + l16] = f2b(acc[c][r]);
        }
    }
}

// ---- agg2: out = A@S2 + b2, F=40, fp64 accum ----
__global__ void agg2_kernel(const unsigned short* __restrict__ S2, const int* __restrict__ offs,
                            const int2* __restrict__ edges,
                            const float* __restrict__ b2, float* __restrict__ out, int n){
    int node = blockIdx.x*4 + (threadIdx.x >> 6);  // one wave per node
    int lane = threadIdx.x & 63;
    if (node >= n) return;
    int e0 = offs[node], e1 = offs[node+1];
    bool act = lane < 20;                // 20 lanes x ushort2 = 40 feats
    double ax = 0.0, ay = 0.0;
    int e = e0;
    for (; e+4 <= e1; e += 4){
        int2 p0=edges[e], p1=edges[e+1], p2=edges[e+2], p3=edges[e+3];
        if (act){
            ushort2 v0 = *(const ushort2*)&S2[(size_t)p0.x*F2P + lane*2];
            ushort2 v1 = *(const ushort2*)&S2[(size_t)p1.x*F2P + lane*2];
            ushort2 v2 = *(const ushort2*)&S2[(size_t)p2.x*F2P + lane*2];
            ushort2 v3 = *(const ushort2*)&S2[(size_t)p3.x*F2P + lane*2];
            double w0=__int_as_float(p0.y), w1=__int_as_float(p1.y);
            double w2=__int_as_float(p2.y), w3=__int_as_float(p3.y);
            ax += w0*b2f(v0.x)+w1*b2f(v1.x)+w2*b2f(v2.x)+w3*b2f(v3.x);
            ay += w0*b2f(v0.y)+w1*b2f(v1.y)+w2*b2f(v2.y)+w3*b2f(v3.y);
        }
    }
    for (; e < e1; e++){
        int2 p = edges[e];
        if (act){
            double w = __int_as_float(p.y);
            ushort2 v = *(const ushort2*)&S2[(size_t)p.x*F2P + lane*2];
            ax += w*b2f(v.x); ay += w*b2f(v.y);
        }
    }
    if (act){
        float2 bb = ((const float2*)b2)[lane];
        float2 o;
        o.x = (float)(ax + (double)bb.x);
        o.y = (float)(ay + (double)bb.y);
        *(float2*)&out[(size_t)node*F2 + lane*2] = o;
    }
}

extern "C" void kernel_launch(void* const* d_in, const int* in_sizes, int n_in,
                              void* d_out, int out_size, void* d_ws, size_t ws_size,
                              hipStream_t stream){
    const float* x    = (const float*)d_in[0];
    const int*   esrc = (const int*)d_in[1];
    const int*   edst = (const int*)d_in[2];
    const float* ew   = (const float*)d_in[3];
    const float* W1   = (const float*)d_in[4];
    const float* b1   = (const float*)d_in[5];
    const float* W2   = (const float*)d_in[6];
    const float* b2   = (const float*)d_in[7];
    float* out = (float*)d_out;
    int N = in_sizes[0] / F0;   // 50000
    int E = in_sizes[1];        // 800000

    char* ws = (char*)d_ws;
    size_t off = 0;
    auto alloc = [&](size_t bytes)->void*{
        void* p = ws + off; off += (bytes + 255) & ~(size_t)255; return p;
    };
    unsigned short* S1 = (unsigned short*)alloc(sizeof(unsigned short)*(size_t)N*F1);  // 12.8 MB
    unsigned short* H  = (unsigned short*)alloc(sizeof(unsigned short)*(size_t)N*F1);  // 12.8 MB
    unsigned short* S2 = (unsigned short*)alloc(sizeof(unsigned short)*(size_t)N*F2P); // 4.8 MB
    unsigned short* W1th = (unsigned short*)alloc(sizeof(unsigned short)*F1*F0);
    unsigned short* W1tl = (unsigned short*)alloc(sizeof(unsigned short)*F1*F0);
    unsigned short* W2th = (unsigned short*)alloc(sizeof(unsigned short)*F2P*F1);
    unsigned short* W2tl = (unsigned short*)alloc(sizeof(unsigned short)*F2P*F1);
    int*   offs  = (int*)alloc(sizeof(int)*(size_t)(N+1));
    int*   cur   = (int*)alloc(sizeof(int)*(size_t)N);
    int2*  edges = (int2*)alloc(sizeof(int2)*(size_t)E);   // 6.4 MB
    int*   bsum  = (int*)alloc(sizeof(int)*64);

    // CSR build (ws re-poisoned each call -> zero counts first)
    hipMemsetAsync(cur, 0, sizeof(int)*(size_t)N, stream);
    hist_kernel<<<(E+255)/256,256,0,stream>>>(edst, cur, E);
    int nb = (N+1023)/1024;     // 49 <= 64
    scan1_kernel<<<nb,256,0,stream>>>(cur, offs, bsum, N);
    scan2_kernel<<<1,64,0,stream>>>(bsum, nb);
    scan3_kernel<<<(N+255)/256,256,0,stream>>>(offs, cur, bsum, N, E);
    scatter_kernel<<<(E+255)/256,256,0,stream>>>(esrc, edst, ew, cur, edges, E);

    // weight prep
    prep_w1<<<(F0*F1)/256,256,0,stream>>>(W1, W1th, W1tl);
    prep_w2<<<(F2P*F1)/256,256,0,stream>>>(W2, W2th, W2tl);

    // layer 1
    gemm1_mfma<<<(N+63)/64,256,0,stream>>>(x, W1th, W1tl, S1, N);
    agg1_kernel<<<(N+3)/4,256,0,stream>>>((const ushort2*)S1, offs, edges, b1, (ushort2*)H, N);
    // layer 2
    gemm2_mfma<<<(N+63)/64,256,0,stream>>>(H, W2th, W2tl, S2, N);
    agg2_kernel<<<(N+3)/4,256,0,stream>>>(S2, offs, edges, b2, out, N);
}

// Round 5
// 355.598 us; speedup vs baseline: 1.4630x; 1.0328x over previous
//
#include <hip/hip_runtime.h>

// GCN 2-layer forward on MI355X (gfx950).
// out = A @ relu(A @ (x@W1) + b1) @ W2 + b2   (A = weighted edge aggregation)
// R5: plain-bf16 MFMA GEMMs (R2 evidence: bf16 absmax == fp32 absmax 0.25 vs
//     thr 1.37) + fp64 aggregation accumulators for bit-determinism under the
//     atomic CSR scatter order. Fused scan2->scan3, fused weight prep.

#define F0 512
#define F1 128
#define F2 40
#define F2P 48   // padded S2 row (bf16)

typedef short bf16x8 __attribute__((ext_vector_type(8)));
typedef float f32x4 __attribute__((ext_vector_type(4)));

// accurate RNE (used for weights, once per call)
static __device__ __forceinline__ unsigned short f2b(float f){
    union { float f; unsigned int u; } x; x.f = f;
    unsigned int u = x.u;
    unsigned int r = (u + 0x7fffu + ((u >> 16) & 1u)) >> 16;
    return (unsigned short)r;
}
// fast round-half-up (activations; differs from RNE only at exact .5 ties)
static __device__ __forceinline__ unsigned short f2b_fast(float f){
    return (unsigned short)((__float_as_uint(f) + 0x8000u) >> 16);
}
// pack two floats -> two bf16 in one dword (2 adds + 1 v_perm)
static __device__ __forceinline__ unsigned int pack2(float a, float b){
    unsigned int ua = __float_as_uint(a) + 0x8000u;
    unsigned int ub = __float_as_uint(b) + 0x8000u;
    return __builtin_amdgcn_perm(ub, ua, 0x07060302u);  // {ub[3],ub[2],ua[3],ua[2]}
}
static __device__ __forceinline__ bf16x8 pack8(float4 v0, float4 v1){
    union { bf16x8 v; unsigned int d[4]; } r;
    r.d[0] = pack2(v0.x, v0.y);
    r.d[1] = pack2(v0.z, v0.w);
    r.d[2] = pack2(v1.x, v1.y);
    r.d[3] = pack2(v1.z, v1.w);
    return r.v;
}
static __device__ __forceinline__ float b2f(unsigned short h){
    union { unsigned int u; float f; } x; x.u = ((unsigned int)h) << 16; return x.f;
}

// ---------------- CSR build ----------------
__global__ void hist_kernel(const int* __restrict__ dst, int* __restrict__ cnt, int E){
    int e = blockIdx.x*256 + threadIdx.x;
    if (e < E) atomicAdd(&cnt[dst[e]], 1);
}

__global__ void scan1_kernel(const int* __restrict__ cnt, int* __restrict__ offs,
                             int* __restrict__ bsum, int n){
    __shared__ int sd[256];
    int tid = threadIdx.x;
    int base = blockIdx.x*1024 + tid*4;
    int c0 = (base+0<n)?cnt[base+0]:0;
    int c1 = (base+1<n)?cnt[base+1]:0;
    int c2 = (base+2<n)?cnt[base+2]:0;
    int c3 = (base+3<n)?cnt[base+3]:0;
    int v1=c0, v2=c0+c1, v3=c0+c1+c2;
    int s = c0+c1+c2+c3;
    sd[tid]=s; __syncthreads();
    for (int off=1; off<256; off<<=1){
        int t = (tid>=off)? sd[tid-off] : 0;
        __syncthreads();
        sd[tid] += t;
        __syncthreads();
    }
    int excl = sd[tid] - s;
    if (base+0<n) offs[base+0]=excl;
    if (base+1<n) offs[base+1]=excl+v1;
    if (base+2<n) offs[base+2]=excl+v2;
    if (base+3<n) offs[base+3]=excl+v3;
    if (tid==255) bsum[blockIdx.x]=sd[255];
}

// scan of per-block sums fused in (wave-0 shuffle prefix over nb<=64 entries)
__global__ void scan3_kernel(int* __restrict__ offs, int* __restrict__ cur,
                             const int* __restrict__ bsum, int n, int E, int nb){
    __shared__ int sexcl;
    int tid = threadIdx.x;
    if (tid < 64){
        int v = (tid < nb) ? bsum[tid] : 0;
        int orig = v;
        #pragma unroll
        for (int off=1; off<64; off<<=1){
            int t = __shfl_up(v, off);
            if (tid >= off) v += t;
        }
        int g = blockIdx.x >> 2;   // 256-thread block -> same 1024-group
        if (tid == g) sexcl = v - orig;
    }
    __syncthreads();
    int i = blockIdx.x*256 + tid;
    if (i<n){ int o = offs[i] + sexcl; offs[i]=o; cur[i]=o; }
    if (i==0) offs[n]=E;
}

__global__ void scatter_kernel(const int* __restrict__ src, const int* __restrict__ dst,
                               const float* __restrict__ w, int* __restrict__ cur,
                               int2* __restrict__ edges, int E){
    int e = blockIdx.x*256+threadIdx.x;
    if (e<E){
        int d = dst[e];
        int pos = atomicAdd(&cur[d],1);
        int2 rec; rec.x = src[e]; rec.y = __float_as_int(w[e]);
        edges[pos] = rec;
    }
}

// ---------------- weight prep (fused W1 + W2 transpose->bf16) ----------------
__global__ void prep_w(const float* __restrict__ W1, const float* __restrict__ W2,
                       unsigned short* __restrict__ W1t, unsigned short* __restrict__ W2t){
    int idx = blockIdx.x*256 + threadIdx.x;
    if (idx < F0*F1){                    // W1 [512][128] -> W1t [128][512]
        int k = idx >> 7, n = idx & 127;
        W1t[(size_t)n*F0 + k] = f2b(W1[idx]);
    } else {
        int j = idx - F0*F1;             // W2 [128][40] -> W2t [48][128]
        if (j < F2P*F1){
            int n = j >> 7, k = j & 127;
            float v = (n < F2) ? W2[(size_t)k*F2 + n] : 0.f;
            W2t[j] = f2b(v);
        }
    }
}

// ---- GEMM1: X[M,512]fp32 @ W1t -> S1 bf16 [M,128] (bf16 MFMA, pipelined) ----
__global__ __launch_bounds__(256) void gemm1_mfma(const float* __restrict__ X,
                                                  const unsigned short* __restrict__ W1t,
                                                  unsigned short* __restrict__ S1, int M){
    __shared__ unsigned short sB[128][72];  // 144B row stride -> 2-way bank alias (free)
    int tid = threadIdx.x;
    int wave = tid >> 6, lane = tid & 63;
    int quad = lane >> 4, l16 = lane & 15;
    int row0 = blockIdx.x * 64;
    int myrow = row0 + wave*16 + l16;
    int arow = min(myrow, M-1);
    const float* xrow = X + (size_t)arow * F0;

    int sn = tid >> 1, shalf = tid & 1;  // B staging: 32 shorts of row sn per thread
    const unsigned short* bsrc = W1t + (size_t)sn*F0 + shalf*32;
    unsigned short* bdst = &sB[sn][shalf*32];

    f32x4 acc[8];
    #pragma unroll
    for (int c=0;c<8;c++) acc[c] = (f32x4){0.f,0.f,0.f,0.f};

    // prologue: tile 0
    float4 a0 = *(const float4*)(xrow + quad*8);
    float4 a1 = *(const float4*)(xrow + quad*8 + 4);
    float4 a2 = *(const float4*)(xrow + 32 + quad*8);
    float4 a3 = *(const float4*)(xrow + 32 + quad*8 + 4);
    {
        float4 b0 = *(const float4*)(bsrc+ 0), b1 = *(const float4*)(bsrc+ 8);
        float4 b2 = *(const float4*)(bsrc+16), b3 = *(const float4*)(bsrc+24);
        *(float4*)(bdst+ 0)=b0; *(float4*)(bdst+ 8)=b1;
        *(float4*)(bdst+16)=b2; *(float4*)(bdst+24)=b3;
    }
    __syncthreads();

    for (int k0 = 0; k0 < F0; k0 += 64){
        bool more = (k0 + 64) < F0;
        float4 na0, na1, na2, na3, nb0, nb1, nb2, nb3;
        if (more){
            const float* nx = xrow + k0 + 64;
            na0 = *(const float4*)(nx + quad*8);
            na1 = *(const float4*)(nx + quad*8 + 4);
            na2 = *(const float4*)(nx + 32 + quad*8);
            na3 = *(const float4*)(nx + 32 + quad*8 + 4);
            const unsigned short* p = bsrc + k0 + 64;
            nb0 = *(const float4*)(p+ 0); nb1 = *(const float4*)(p+ 8);
            nb2 = *(const float4*)(p+16); nb3 = *(const float4*)(p+24);
        }
        bf16x8 af0 = pack8(a0, a1);
        bf16x8 af1 = pack8(a2, a3);
        #pragma unroll
        for (int c=0;c<8;c++){
            bf16x8 b0 = *(bf16x8*)&sB[c*16 + l16][quad*8];
            bf16x8 b1 = *(bf16x8*)&sB[c*16 + l16][32 + quad*8];
            acc[c] = __builtin_amdgcn_mfma_f32_16x16x32_bf16(af0, b0, acc[c], 0, 0, 0);
            acc[c] = __builtin_amdgcn_mfma_f32_16x16x32_bf16(af1, b1, acc[c], 0, 0, 0);
        }
        if (more){
            __syncthreads();
            *(float4*)(bdst+ 0)=nb0; *(float4*)(bdst+ 8)=nb1;
            *(float4*)(bdst+16)=nb2; *(float4*)(bdst+24)=nb3;
            __syncthreads();
            a0 = na0; a1 = na1; a2 = na2; a3 = na3;
        }
    }
    // C/D: col = c*16 + l16, row = quad*4 + r
    #pragma unroll
    for (int c=0;c<8;c++){
        #pragma unroll
        for (int r=0;r<4;r++){
            int grow = row0 + wave*16 + quad*4 + r;
            if (grow < M) S1[(size_t)grow*F1 + c*16 + l16] = f2b_fast(acc[c][r]);
        }
    }
}

// ---- agg1: H = relu(A@S1 + b1) bf16, F=128, fp64 accum ----
__global__ void agg1_kernel(const ushort2* __restrict__ S1, const int* __restrict__ offs,
                            const int2* __restrict__ edges,
                            const float* __restrict__ b1, ushort2* __restrict__ H, int n){
    int node = blockIdx.x*4 + (threadIdx.x >> 6);   // one wave per node
    int lane = threadIdx.x & 63;
    if (node >= n) return;
    int e0 = offs[node], e1 = offs[node+1];
    double ax = 0.0, ay = 0.0;
    int e = e0;
    for (; e+8 <= e1; e += 8){
        int2 p0=edges[e],   p1=edges[e+1], p2=edges[e+2], p3=edges[e+3];
        int2 p4=edges[e+4], p5=edges[e+5], p6=edges[e+6], p7=edges[e+7];
        ushort2 v0 = S1[(size_t)p0.x*64 + lane];
        ushort2 v1 = S1[(size_t)p1.x*64 + lane];
        ushort2 v2 = S1[(size_t)p2.x*64 + lane];
        ushort2 v3 = S1[(size_t)p3.x*64 + lane];
        ushort2 v4 = S1[(size_t)p4.x*64 + lane];
        ushort2 v5 = S1[(size_t)p5.x*64 + lane];
        ushort2 v6 = S1[(size_t)p6.x*64 + lane];
        ushort2 v7 = S1[(size_t)p7.x*64 + lane];
        double w0=__int_as_float(p0.y), w1=__int_as_float(p1.y);
        double w2=__int_as_float(p2.y), w3=__int_as_float(p3.y);
        double w4=__int_as_float(p4.y), w5=__int_as_float(p5.y);
        double w6=__int_as_float(p6.y), w7=__int_as_float(p7.y);
        ax += w0*b2f(v0.x)+w1*b2f(v1.x)+w2*b2f(v2.x)+w3*b2f(v3.x)
            + w4*b2f(v4.x)+w5*b2f(v5.x)+w6*b2f(v6.x)+w7*b2f(v7.x);
        ay += w0*b2f(v0.y)+w1*b2f(v1.y)+w2*b2f(v2.y)+w3*b2f(v3.y)
            + w4*b2f(v4.y)+w5*b2f(v5.y)+w6*b2f(v6.y)+w7*b2f(v7.y);
    }
    for (; e < e1; e++){
        int2 p = edges[e];
        double w = __int_as_float(p.y);
        ushort2 v = S1[(size_t)p.x*64 + lane];
        ax += w*b2f(v.x); ay += w*b2f(v.y);
    }
    float2 bb = ((const float2*)b1)[lane];
    float vx = (float)(ax + (double)bb.x);
    float vy = (float)(ay + (double)bb.y);
    ushort2 o;
    o.x = f2b_fast(vx > 0.f ? vx : 0.f);
    o.y = f2b_fast(vy > 0.f ? vy : 0.f);
    H[(size_t)node*64 + lane] = o;
}

// ---- GEMM2: H bf16 [M,128] @ W2t -> S2 bf16 [M,48] ----
__global__ __launch_bounds__(256) void gemm2_mfma(const unsigned short* __restrict__ H,
                                                  const unsigned short* __restrict__ W2t,
                                                  unsigned short* __restrict__ S2, int M){
    __shared__ unsigned short sB[48][136];
    int tid = threadIdx.x;
    int wave = tid >> 6, lane = tid & 63;
    int quad = lane >> 4, l16 = lane & 15;
    for (int i = tid; i < 48*16; i += 256){
        int nn = i >> 4, p = i & 15;
        *(float4*)&sB[nn][p*8] = *(const float4*)&W2t[(size_t)nn*F1 + p*8];
    }
    int row0 = blockIdx.x * 64;
    int myrow = row0 + wave*16 + l16;
    int arow = min(myrow, M-1);
    const unsigned short* hrow = H + (size_t)arow * F1;
    bf16x8 a[4];
    #pragma unroll
    for (int ks=0; ks<4; ks++) a[ks] = *(const bf16x8*)(hrow + ks*32 + quad*8);
    __syncthreads();
    f32x4 acc[3];
    #pragma unroll
    for (int c=0;c<3;c++) acc[c] = (f32x4){0.f,0.f,0.f,0.f};
    #pragma unroll
    for (int ks=0; ks<4; ks++){
        #pragma unroll
        for (int c=0;c<3;c++){
            bf16x8 b = *(bf16x8*)&sB[c*16 + l16][ks*32 + quad*8];
            acc[c] = __builtin_amdgcn_mfma_f32_16x16x32_bf16(a[ks], b, acc[c], 0, 0, 0);
        }
    }
    #pragma unroll
    for (int c=0;c<3;c++){
        #pragma unroll
        for (int r=0;r<4;r++){
            int grow = row0 + wave*16 + quad*4 + r;
            if (grow < M) S2[(size_t)grow*F2P + c*16 + l16] = f2b_fast(acc[c][r]);
        }
    }
}

// ---- agg2: out = A@S2 + b2, F=40, fp64 accum ----
__global__ void agg2_kernel(const unsigned short* __restrict__ S2, const int* __restrict__ offs,
                            const int2* __restrict__ edges,
                            const float* __restrict__ b2, float* __restrict__ out, int n){
    int node = blockIdx.x*4 + (threadIdx.x >> 6);  // one wave per node
    int lane = threadIdx.x & 63;
    if (node >= n) return;
    int e0 = offs[node], e1 = offs[node+1];
    bool act = lane < 20;                // 20 lanes x ushort2 = 40 feats
    double ax = 0.0, ay = 0.0;
    int e = e0;
    for (; e+4 <= e1; e += 4){
        int2 p0=edges[e], p1=edges[e+1], p2=edges[e+2], p3=edges[e+3];
        if (act){
            ushort2 v0 = *(const ushort2*)&S2[(size_t)p0.x*F2P + lane*2];
            ushort2 v1 = *(const ushort2*)&S2[(size_t)p1.x*F2P + lane*2];
            ushort2 v2 = *(const ushort2*)&S2[(size_t)p2.x*F2P + lane*2];
            ushort2 v3 = *(const ushort2*)&S2[(size_t)p3.x*F2P + lane*2];
            double w0=__int_as_float(p0.y), w1=__int_as_float(p1.y);
            double w2=__int_as_float(p2.y), w3=__int_as_float(p3.y);
            ax += w0*b2f(v0.x)+w1*b2f(v1.x)+w2*b2f(v2.x)+w3*b2f(v3.x);
            ay += w0*b2f(v0.y)+w1*b2f(v1.y)+w2*b2f(v2.y)+w3*b2f(v3.y);
        }
    }
    for (; e < e1; e++){
        int2 p = edges[e];
        if (act){
            double w = __int_as_float(p.y);
            ushort2 v = *(const ushort2*)&S2[(size_t)p.x*F2P + lane*2];
            ax += w*b2f(v.x); ay += w*b2f(v.y);
        }
    }
    if (act){
        float2 bb = ((const float2*)b2)[lane];
        float2 o;
        o.x = (float)(ax + (double)bb.x);
        o.y = (float)(ay + (double)bb.y);
        *(float2*)&out[(size_t)node*F2 + lane*2] = o;
    }
}

extern "C" void kernel_launch(void* const* d_in, const int* in_sizes, int n_in,
                              void* d_out, int out_size, void* d_ws, size_t ws_size,
                              hipStream_t stream){
    const float* x    = (const float*)d_in[0];
    const int*   esrc = (const int*)d_in[1];
    const int*   edst = (const int*)d_in[2];
    const float* ew   = (const float*)d_in[3];
    const float* W1   = (const float*)d_in[4];
    const float* b1   = (const float*)d_in[5];
    const float* W2   = (const float*)d_in[6];
    const float* b2   = (const float*)d_in[7];
    float* out = (float*)d_out;
    int N = in_sizes[0] / F0;   // 50000
    int E = in_sizes[1];        // 800000

    char* ws = (char*)d_ws;
    size_t off = 0;
    auto alloc = [&](size_t bytes)->void*{
        void* p = ws + off; off += (bytes + 255) & ~(size_t)255; return p;
    };
    unsigned short* S1 = (unsigned short*)alloc(sizeof(unsigned short)*(size_t)N*F1);  // 12.8 MB
    unsigned short* H  = (unsigned short*)alloc(sizeof(unsigned short)*(size_t)N*F1);  // 12.8 MB
    unsigned short* S2 = (unsigned short*)alloc(sizeof(unsigned short)*(size_t)N*F2P); // 4.8 MB
    unsigned short* W1t = (unsigned short*)alloc(sizeof(unsigned short)*F1*F0);
    unsigned short* W2t = (unsigned short*)alloc(sizeof(unsigned short)*F2P*F1);
    int*   offs  = (int*)alloc(sizeof(int)*(size_t)(N+1));
    int*   cur   = (int*)alloc(sizeof(int)*(size_t)N);
    int2*  edges = (int2*)alloc(sizeof(int2)*(size_t)E);   // 6.4 MB
    int*   bsum  = (int*)alloc(sizeof(int)*64);

    // CSR build (ws re-poisoned each call -> zero counts first)
    hipMemsetAsync(cur, 0, sizeof(int)*(size_t)N, stream);
    hist_kernel<<<(E+255)/256,256,0,stream>>>(edst, cur, E);
    int nb = (N+1023)/1024;     // 49 <= 64
    scan1_kernel<<<nb,256,0,stream>>>(cur, offs, bsum, N);
    scan3_kernel<<<(N+255)/256,256,0,stream>>>(offs, cur, bsum, N, E, nb);
    scatter_kernel<<<(E+255)/256,256,0,stream>>>(esrc, edst, ew, cur, edges, E);

    // weight prep (fused)
    prep_w<<<(F0*F1 + F2P*F1 + 255)/256,256,0,stream>>>(W1, W2, W1t, W2t);

    // layer 1
    gemm1_mfma<<<(N+63)/64,256,0,stream>>>(x, W1t, S1, N);
    agg1_kernel<<<(N+3)/4,256,0,stream>>>((const ushort2*)S1, offs, edges, b1, (ushort2*)H, N);
    // layer 2
    gemm2_mfma<<<(N+63)/64,256,0,stream>>>(H, W2t, S2, N);
    agg2_kernel<<<(N+3)/4,256,0,stream>>>(S2, offs, edges, b2, out, N);
}

// Round 6
// 344.620 us; speedup vs baseline: 1.5096x; 1.0319x over previous
//
#include <hip/hip_runtime.h>

// GCN 2-layer forward on MI355X (gfx950).
// out = A @ relu(A @ (x@W1) + b1) @ W2 + b2   (A = weighted edge aggregation)
// R6: 4B packed edge records (src:u16 | fp16 weight), wide-lane aggregation
//     (agg1: 2 edges/wave-iter w/ ushort4 loads; agg2: 4 edges/wave-iter),
//     fp64 partial accumulators + shuffle combine (deterministic output).

#define F0 512
#define F1 128
#define F2 40
#define F2P 48   // padded S2 row (bf16)

typedef short bf16x8 __attribute__((ext_vector_type(8)));
typedef float f32x4 __attribute__((ext_vector_type(4)));

// accurate RNE bf16 (weights, once per call)
static __device__ __forceinline__ unsigned short f2b(float f){
    union { float f; unsigned int u; } x; x.f = f;
    unsigned int u = x.u;
    unsigned int r = (u + 0x7fffu + ((u >> 16) & 1u)) >> 16;
    return (unsigned short)r;
}
// fast round-half-up bf16 (activations)
static __device__ __forceinline__ unsigned short f2b_fast(float f){
    return (unsigned short)((__float_as_uint(f) + 0x8000u) >> 16);
}
static __device__ __forceinline__ unsigned int pack2(float a, float b){
    unsigned int ua = __float_as_uint(a) + 0x8000u;
    unsigned int ub = __float_as_uint(b) + 0x8000u;
    return __builtin_amdgcn_perm(ub, ua, 0x07060302u);
}
static __device__ __forceinline__ bf16x8 pack8(float4 v0, float4 v1){
    union { bf16x8 v; unsigned int d[4]; } r;
    r.d[0] = pack2(v0.x, v0.y);
    r.d[1] = pack2(v0.z, v0.w);
    r.d[2] = pack2(v1.x, v1.y);
    r.d[3] = pack2(v1.z, v1.w);
    return r.v;
}
static __device__ __forceinline__ float b2f(unsigned short h){
    union { unsigned int u; float f; } x; x.u = ((unsigned int)h) << 16; return x.f;
}
// fp16 pack/unpack for edge weights (w in [0,1): rel err 2^-11)
static __device__ __forceinline__ unsigned short f2h(float f){
    union { _Float16 h; unsigned short u; } x; x.h = (_Float16)f; return x.u;
}
static __device__ __forceinline__ float h2f(unsigned short u){
    union { unsigned short u; _Float16 h; } x; x.u = u; return (float)x.h;
}

// ---------------- CSR build ----------------
__global__ void hist_kernel(const int* __restrict__ dst, int* __restrict__ cnt, int E){
    int e = blockIdx.x*256 + threadIdx.x;
    if (e < E) atomicAdd(&cnt[dst[e]], 1);
}

__global__ void scan1_kernel(const int* __restrict__ cnt, int* __restrict__ offs,
                             int* __restrict__ bsum, int n){
    __shared__ int sd[256];
    int tid = threadIdx.x;
    int base = blockIdx.x*1024 + tid*4;
    int c0 = (base+0<n)?cnt[base+0]:0;
    int c1 = (base+1<n)?cnt[base+1]:0;
    int c2 = (base+2<n)?cnt[base+2]:0;
    int c3 = (base+3<n)?cnt[base+3]:0;
    int v1=c0, v2=c0+c1, v3=c0+c1+c2;
    int s = c0+c1+c2+c3;
    sd[tid]=s; __syncthreads();
    for (int off=1; off<256; off<<=1){
        int t = (tid>=off)? sd[tid-off] : 0;
        __syncthreads();
        sd[tid] += t;
        __syncthreads();
    }
    int excl = sd[tid] - s;
    if (base+0<n) offs[base+0]=excl;
    if (base+1<n) offs[base+1]=excl+v1;
    if (base+2<n) offs[base+2]=excl+v2;
    if (base+3<n) offs[base+3]=excl+v3;
    if (tid==255) bsum[blockIdx.x]=sd[255];
}

// block-sum prefix fused in (wave-0 shuffle scan over nb<=64 entries)
__global__ void scan3_kernel(int* __restrict__ offs, int* __restrict__ cur,
                             const int* __restrict__ bsum, int n, int E, int nb){
    __shared__ int sexcl;
    int tid = threadIdx.x;
    if (tid < 64){
        int v = (tid < nb) ? bsum[tid] : 0;
        int orig = v;
        #pragma unroll
        for (int off=1; off<64; off<<=1){
            int t = __shfl_up(v, off);
            if (tid >= off) v += t;
        }
        int g = blockIdx.x >> 2;
        if (tid == g) sexcl = v - orig;
    }
    __syncthreads();
    int i = blockIdx.x*256 + tid;
    if (i<n){ int o = offs[i] + sexcl; offs[i]=o; cur[i]=o; }
    if (i==0) offs[n]=E;
}

__global__ void scatter_kernel(const int* __restrict__ src, const int* __restrict__ dst,
                               const float* __restrict__ w, int* __restrict__ cur,
                               unsigned int* __restrict__ edges, int E){
    int e = blockIdx.x*256+threadIdx.x;
    if (e<E){
        int d = dst[e];
        int pos = atomicAdd(&cur[d],1);
        edges[pos] = ((unsigned int)src[e] << 16) | (unsigned int)f2h(w[e]);
    }
}

// ---------------- weight prep (fused W1 + W2 transpose->bf16) ----------------
__global__ void prep_w(const float* __restrict__ W1, const float* __restrict__ W2,
                       unsigned short* __restrict__ W1t, unsigned short* __restrict__ W2t){
    int idx = blockIdx.x*256 + threadIdx.x;
    if (idx < F0*F1){                    // W1 [512][128] -> W1t [128][512]
        int k = idx >> 7, n = idx & 127;
        W1t[(size_t)n*F0 + k] = f2b(W1[idx]);
    } else {
        int j = idx - F0*F1;             // W2 [128][40] -> W2t [48][128]
        if (j < F2P*F1){
            int n = j >> 7, k = j & 127;
            float v = (n < F2) ? W2[(size_t)k*F2 + n] : 0.f;
            W2t[j] = f2b(v);
        }
    }
}

// ---- GEMM1: X[M,512]fp32 @ W1t -> S1 bf16 [M,128] (bf16 MFMA, pipelined) ----
__global__ __launch_bounds__(256) void gemm1_mfma(const float* __restrict__ X,
                                                  const unsigned short* __restrict__ W1t,
                                                  unsigned short* __restrict__ S1, int M){
    __shared__ unsigned short sB[128][72];
    int tid = threadIdx.x;
    int wave = tid >> 6, lane = tid & 63;
    int quad = lane >> 4, l16 = lane & 15;
    int row0 = blockIdx.x * 64;
    int myrow = row0 + wave*16 + l16;
    int arow = min(myrow, M-1);
    const float* xrow = X + (size_t)arow * F0;

    int sn = tid >> 1, shalf = tid & 1;
    const unsigned short* bsrc = W1t + (size_t)sn*F0 + shalf*32;
    unsigned short* bdst = &sB[sn][shalf*32];

    f32x4 acc[8];
    #pragma unroll
    for (int c=0;c<8;c++) acc[c] = (f32x4){0.f,0.f,0.f,0.f};

    float4 a0 = *(const float4*)(xrow + quad*8);
    float4 a1 = *(const float4*)(xrow + quad*8 + 4);
    float4 a2 = *(const float4*)(xrow + 32 + quad*8);
    float4 a3 = *(const float4*)(xrow + 32 + quad*8 + 4);
    {
        float4 b0 = *(const float4*)(bsrc+ 0), b1 = *(const float4*)(bsrc+ 8);
        float4 b2 = *(const float4*)(bsrc+16), b3 = *(const float4*)(bsrc+24);
        *(float4*)(bdst+ 0)=b0; *(float4*)(bdst+ 8)=b1;
        *(float4*)(bdst+16)=b2; *(float4*)(bdst+24)=b3;
    }
    __syncthreads();

    for (int k0 = 0; k0 < F0; k0 += 64){
        bool more = (k0 + 64) < F0;
        float4 na0, na1, na2, na3, nb0, nb1, nb2, nb3;
        if (more){
            const float* nx = xrow + k0 + 64;
            na0 = *(const float4*)(nx + quad*8);
            na1 = *(const float4*)(nx + quad*8 + 4);
            na2 = *(const float4*)(nx + 32 + quad*8);
            na3 = *(const float4*)(nx + 32 + quad*8 + 4);
            const unsigned short* p = bsrc + k0 + 64;
            nb0 = *(const float4*)(p+ 0); nb1 = *(const float4*)(p+ 8);
            nb2 = *(const float4*)(p+16); nb3 = *(const float4*)(p+24);
        }
        bf16x8 af0 = pack8(a0, a1);
        bf16x8 af1 = pack8(a2, a3);
        #pragma unroll
        for (int c=0;c<8;c++){
            bf16x8 b0 = *(bf16x8*)&sB[c*16 + l16][quad*8];
            bf16x8 b1 = *(bf16x8*)&sB[c*16 + l16][32 + quad*8];
            acc[c] = __builtin_amdgcn_mfma_f32_16x16x32_bf16(af0, b0, acc[c], 0, 0, 0);
            acc[c] = __builtin_amdgcn_mfma_f32_16x16x32_bf16(af1, b1, acc[c], 0, 0, 0);
        }
        if (more){
            __syncthreads();
            *(float4*)(bdst+ 0)=nb0; *(float4*)(bdst+ 8)=nb1;
            *(float4*)(bdst+16)=nb2; *(float4*)(bdst+24)=nb3;
            __syncthreads();
            a0 = na0; a1 = na1; a2 = na2; a3 = na3;
        }
    }
    #pragma unroll
    for (int c=0;c<8;c++){
        #pragma unroll
        for (int r=0;r<4;r++){
            int grow = row0 + wave*16 + quad*4 + r;
            if (grow < M) S1[(size_t)grow*F1 + c*16 + l16] = f2b_fast(acc[c][r]);
        }
    }
}

// ---- agg1: H = relu(A@S1 + b1) bf16, F=128 ----
// Two 32-lane halves process alternating edges; lane fl covers feats fl*4..+3
// via ushort4 loads. fp64 partials, combined with shfl (order-safe).
__global__ void agg1_kernel(const unsigned short* __restrict__ S1, const int* __restrict__ offs,
                            const unsigned int* __restrict__ edges,
                            const float* __restrict__ b1, unsigned short* __restrict__ H, int n){
    int node = blockIdx.x*4 + (threadIdx.x >> 6);   // one wave per node
    int lane = threadIdx.x & 63;
    if (node >= n) return;
    int half = lane >> 5, fl = lane & 31;
    int e0 = offs[node], e1 = offs[node+1];
    double a0=0.0, a1=0.0, a2=0.0, a3=0.0;
    int e = e0;
    for (; e+8 <= e1; e += 8){
        unsigned int rA = edges[e   + half];
        unsigned int rB = edges[e+2 + half];
        unsigned int rC = edges[e+4 + half];
        unsigned int rD = edges[e+6 + half];
        ushort4 vA = *(const ushort4*)&S1[((size_t)(rA>>16))*F1 + fl*4];
        ushort4 vB = *(const ushort4*)&S1[((size_t)(rB>>16))*F1 + fl*4];
        ushort4 vC = *(const ushort4*)&S1[((size_t)(rC>>16))*F1 + fl*4];
        ushort4 vD = *(const ushort4*)&S1[((size_t)(rD>>16))*F1 + fl*4];
        double wA = h2f((unsigned short)rA), wB = h2f((unsigned short)rB);
        double wC = h2f((unsigned short)rC), wD = h2f((unsigned short)rD);
        a0 += wA*b2f(vA.x) + wB*b2f(vB.x) + wC*b2f(vC.x) + wD*b2f(vD.x);
        a1 += wA*b2f(vA.y) + wB*b2f(vB.y) + wC*b2f(vC.y) + wD*b2f(vD.y);
        a2 += wA*b2f(vA.z) + wB*b2f(vB.z) + wC*b2f(vC.z) + wD*b2f(vD.z);
        a3 += wA*b2f(vA.w) + wB*b2f(vB.w) + wC*b2f(vC.w) + wD*b2f(vD.w);
    }
    for (; e < e1; e += 2){
        int ee = e + half;
        if (ee < e1){
            unsigned int r = edges[ee];
            ushort4 v = *(const ushort4*)&S1[((size_t)(r>>16))*F1 + fl*4];
            double w = h2f((unsigned short)r);
            a0 += w*b2f(v.x); a1 += w*b2f(v.y); a2 += w*b2f(v.z); a3 += w*b2f(v.w);
        }
    }
    a0 += __shfl_down(a0, 32);
    a1 += __shfl_down(a1, 32);
    a2 += __shfl_down(a2, 32);
    a3 += __shfl_down(a3, 32);
    if (lane < 32){
        float4 bb = *(const float4*)&b1[fl*4];
        float o0 = (float)(a0 + (double)bb.x);
        float o1 = (float)(a1 + (double)bb.y);
        float o2 = (float)(a2 + (double)bb.z);
        float o3 = (float)(a3 + (double)bb.w);
        o0 = o0>0.f?o0:0.f; o1 = o1>0.f?o1:0.f;
        o2 = o2>0.f?o2:0.f; o3 = o3>0.f?o3:0.f;
        union { ushort4 v; unsigned int d[2]; } o;
        o.d[0] = pack2(o0, o1);
        o.d[1] = pack2(o2, o3);
        *(ushort4*)&H[(size_t)node*F1 + fl*4] = o.v;
    }
}

// ---- GEMM2: H bf16 [M,128] @ W2t -> S2 bf16 [M,48] ----
__global__ __launch_bounds__(256) void gemm2_mfma(const unsigned short* __restrict__ H,
                                                  const unsigned short* __restrict__ W2t,
                                                  unsigned short* __restrict__ S2, int M){
    __shared__ unsigned short sB[48][136];
    int tid = threadIdx.x;
    int wave = tid >> 6, lane = tid & 63;
    int quad = lane >> 4, l16 = lane & 15;
    for (int i = tid; i < 48*16; i += 256){
        int nn = i >> 4, p = i & 15;
        *(float4*)&sB[nn][p*8] = *(const float4*)&W2t[(size_t)nn*F1 + p*8];
    }
    int row0 = blockIdx.x * 64;
    int myrow = row0 + wave*16 + l16;
    int arow = min(myrow, M-1);
    const unsigned short* hrow = H + (size_t)arow * F1;
    bf16x8 a[4];
    #pragma unroll
    for (int ks=0; ks<4; ks++) a[ks] = *(const bf16x8*)(hrow + ks*32 + quad*8);
    __syncthreads();
    f32x4 acc[3];
    #pragma unroll
    for (int c=0;c<3;c++) acc[c] = (f32x4){0.f,0.f,0.f,0.f};
    #pragma unroll
    for (int ks=0; ks<4; ks++){
        #pragma unroll
        for (int c=0;c<3;c++){
            bf16x8 b = *(bf16x8*)&sB[c*16 + l16][ks*32 + quad*8];
            acc[c] = __builtin_amdgcn_mfma_f32_16x16x32_bf16(a[ks], b, acc[c], 0, 0, 0);
        }
    }
    #pragma unroll
    for (int c=0;c<3;c++){
        #pragma unroll
        for (int r=0;r<4;r++){
            int grow = row0 + wave*16 + quad*4 + r;
            if (grow < M) S2[(size_t)grow*F2P + c*16 + l16] = f2b_fast(acc[c][r]);
        }
    }
}

// ---- agg2: out = A@S2 + b2, F=40 ----
// Four 16-lane groups process 4 edges/iter; lane gl<10 covers feats gl*4..+3.
__global__ void agg2_kernel(const unsigned short* __restrict__ S2, const int* __restrict__ offs,
                            const unsigned int* __restrict__ edges,
                            const float* __restrict__ b2, float* __restrict__ out, int n){
    int node = blockIdx.x*4 + (threadIdx.x >> 6);  // one wave per node
    int lane = threadIdx.x & 63;
    if (node >= n) return;
    int grp = lane >> 4, gl = lane & 15;
    bool act = gl < 10;
    int e0 = offs[node], e1 = offs[node+1];
    double a0=0.0, a1=0.0, a2=0.0, a3=0.0;
    for (int e = e0; e < e1; e += 4){
        int ee = e + grp;
        if (ee < e1 && act){
            unsigned int r = edges[ee];
            ushort4 v = *(const ushort4*)&S2[((size_t)(r>>16))*F2P + gl*4];
            double w = h2f((unsigned short)r);
            a0 += w*b2f(v.x); a1 += w*b2f(v.y); a2 += w*b2f(v.z); a3 += w*b2f(v.w);
        }
    }
    a0 += __shfl_down(a0, 32); a0 += __shfl_down(a0, 16);
    a1 += __shfl_down(a1, 32); a1 += __shfl_down(a1, 16);
    a2 += __shfl_down(a2, 32); a2 += __shfl_down(a2, 16);
    a3 += __shfl_down(a3, 32); a3 += __shfl_down(a3, 16);
    if (lane < 10){
        float4 bb = *(const float4*)&b2[lane*4];
        float4 o;
        o.x = (float)(a0 + (double)bb.x);
        o.y = (float)(a1 + (double)bb.y);
        o.z = (float)(a2 + (double)bb.z);
        o.w = (float)(a3 + (double)bb.w);
        *(float4*)&out[(size_t)node*F2 + lane*4] = o;
    }
}

extern "C" void kernel_launch(void* const* d_in, const int* in_sizes, int n_in,
                              void* d_out, int out_size, void* d_ws, size_t ws_size,
                              hipStream_t stream){
    const float* x    = (const float*)d_in[0];
    const int*   esrc = (const int*)d_in[1];
    const int*   edst = (const int*)d_in[2];
    const float* ew   = (const float*)d_in[3];
    const float* W1   = (const float*)d_in[4];
    const float* b1   = (const float*)d_in[5];
    const float* W2   = (const float*)d_in[6];
    const float* b2   = (const float*)d_in[7];
    float* out = (float*)d_out;
    int N = in_sizes[0] / F0;   // 50000
    int E = in_sizes[1];        // 800000

    char* ws = (char*)d_ws;
    size_t off = 0;
    auto alloc = [&](size_t bytes)->void*{
        void* p = ws + off; off += (bytes + 255) & ~(size_t)255; return p;
    };
    unsigned short* S1 = (unsigned short*)alloc(sizeof(unsigned short)*(size_t)N*F1);  // 12.8 MB
    unsigned short* H  = (unsigned short*)alloc(sizeof(unsigned short)*(size_t)N*F1);  // 12.8 MB
    unsigned short* S2 = (unsigned short*)alloc(sizeof(unsigned short)*(size_t)N*F2P); // 4.8 MB
    unsigned short* W1t = (unsigned short*)alloc(sizeof(unsigned short)*F1*F0);
    unsigned short* W2t = (unsigned short*)alloc(sizeof(unsigned short)*F2P*F1);
    int*   offs  = (int*)alloc(sizeof(int)*(size_t)(N+1));
    int*   cur   = (int*)alloc(sizeof(int)*(size_t)N);
    unsigned int* edges = (unsigned int*)alloc(sizeof(unsigned int)*(size_t)E);  // 3.2 MB
    int*   bsum  = (int*)alloc(sizeof(int)*64);

    // CSR build (ws re-poisoned each call -> zero counts first)
    hipMemsetAsync(cur, 0, sizeof(int)*(size_t)N, stream);
    hist_kernel<<<(E+255)/256,256,0,stream>>>(edst, cur, E);
    int nb = (N+1023)/1024;     // 49 <= 64
    scan1_kernel<<<nb,256,0,stream>>>(cur, offs, bsum, N);
    scan3_kernel<<<(N+255)/256,256,0,stream>>>(offs, cur, bsum, N, E, nb);
    scatter_kernel<<<(E+255)/256,256,0,stream>>>(esrc, edst, ew, cur, edges, E);

    // weight prep (fused)
    prep_w<<<(F0*F1 + F2P*F1 + 255)/256,256,0,stream>>>(W1, W2, W1t, W2t);

    // layer 1
    gemm1_mfma<<<(N+63)/64,256,0,stream>>>(x, W1t, S1, N);
    agg1_kernel<<<(N+3)/4,256,0,stream>>>(S1, offs, edges, b1, H, N);
    // layer 2
    gemm2_mfma<<<(N+63)/64,256,0,stream>>>(H, W2t, S2, N);
    agg2_kernel<<<(N+3)/4,256,0,stream>>>(S2, offs, edges, b2, out, N);
}

// Round 7
// 322.631 us; speedup vs baseline: 1.6125x; 1.0682x over previous
//
#include <hip/hip_runtime.h>

// GCN 2-layer forward on MI355X (gfx950).
// out = A @ relu(A @ (x@W1) + b1) @ W2 + b2   (A = weighted edge aggregation)
// R7: latency-focused round.
//  - gemm1: BK=128 phases (8 barriers total vs 16), 34.8KB LDS (3-4 blocks/CU),
//    cross-phase A-register prefetch (8 indep HBM loads in flight per wave).
//  - CSR: 8-way sharded histogram (contention 16->2) + saved per-edge slots ->
//    scatter with NO atomics. memset folded into prep_w. 9 dispatches.
//  - aggs unchanged from R6 (near L3 gather floor; fp64 accum = deterministic).

#define F0 512
#define F1 128
#define F2 40
#define F2P 48   // padded S2 row (bf16)

typedef short bf16x8 __attribute__((ext_vector_type(8)));
typedef float f32x4 __attribute__((ext_vector_type(4)));

// accurate RNE bf16 (weights, once per call)
static __device__ __forceinline__ unsigned short f2b(float f){
    union { float f; unsigned int u; } x; x.f = f;
    unsigned int u = x.u;
    unsigned int r = (u + 0x7fffu + ((u >> 16) & 1u)) >> 16;
    return (unsigned short)r;
}
// fast round-half-up bf16 (activations)
static __device__ __forceinline__ unsigned short f2b_fast(float f){
    return (unsigned short)((__float_as_uint(f) + 0x8000u) >> 16);
}
static __device__ __forceinline__ unsigned int pack2(float a, float b){
    unsigned int ua = __float_as_uint(a) + 0x8000u;
    unsigned int ub = __float_as_uint(b) + 0x8000u;
    return __builtin_amdgcn_perm(ub, ua, 0x07060302u);
}
static __device__ __forceinline__ bf16x8 pack8(float4 v0, float4 v1){
    union { bf16x8 v; unsigned int d[4]; } r;
    r.d[0] = pack2(v0.x, v0.y);
    r.d[1] = pack2(v0.z, v0.w);
    r.d[2] = pack2(v1.x, v1.y);
    r.d[3] = pack2(v1.z, v1.w);
    return r.v;
}
static __device__ __forceinline__ float b2f(unsigned short h){
    union { unsigned int u; float f; } x; x.u = ((unsigned int)h) << 16; return x.f;
}
// fp16 pack/unpack for edge weights (w in [0,1): rel err 2^-11)
static __device__ __forceinline__ unsigned short f2h(float f){
    union { _Float16 h; unsigned short u; } x; x.h = (_Float16)f; return x.u;
}
static __device__ __forceinline__ float h2f(unsigned short u){
    union { unsigned short u; _Float16 h; } x; x.u = u; return (float)x.h;
}

// ---------------- weight prep + cnt8 zero (fused) ----------------
__global__ void prep_w(const float* __restrict__ W1, const float* __restrict__ W2,
                       unsigned short* __restrict__ W1t, unsigned short* __restrict__ W2t,
                       int* __restrict__ cnt8, int n8){
    int idx = blockIdx.x*256 + threadIdx.x;   // grid covers max(400000, 71680)
    if (idx < n8) cnt8[idx] = 0;
    if (idx < F0*F1){                    // W1 [512][128] -> W1t [128][512]
        int k = idx >> 7, n = idx & 127;
        W1t[(size_t)n*F0 + k] = f2b(W1[idx]);
    } else if (idx < F0*F1 + F2P*F1){    // W2 [128][40] -> W2t [48][128]
        int j = idx - F0*F1;
        int n = j >> 7, k = j & 127;
        float v = (n < F2) ? W2[(size_t)k*F2 + n] : 0.f;
        W2t[j] = f2b(v);
    }
}

// ---------------- CSR build: sharded hist (8 shards/node) ----------------
__global__ void hist_kernel(const int* __restrict__ dst, int* __restrict__ cnt8,
                            unsigned short* __restrict__ slot, int E){
    int e = blockIdx.x*256 + threadIdx.x;
    if (e < E){
        int d = dst[e];
        int s = e & 7;                       // shard by low edge bits
        slot[e] = (unsigned short)atomicAdd(&cnt8[d*8 + s], 1);
    }
}

// per-1024-node chunk scan; also emits per-node shard local prefixes
__global__ void scan1_kernel(const int* __restrict__ cnt8, int* __restrict__ offs,
                             unsigned short* __restrict__ lsp, int* __restrict__ bsum, int n){
    __shared__ int sd[256];
    int tid = threadIdx.x;
    int base = blockIdx.x*1024 + tid*4;
    int t[4];
    #pragma unroll
    for (int j=0;j<4;j++){
        int node = base+j;
        int tot = 0;
        if (node < n){
            int4 c0 = *(const int4*)&cnt8[(size_t)node*8];
            int4 c1 = *(const int4*)&cnt8[(size_t)node*8+4];
            unsigned short lp0=0, lp1, lp2, lp3, lp4, lp5, lp6, lp7;
            int run = c0.x; lp1=(unsigned short)run;
            run += c0.y; lp2=(unsigned short)run;
            run += c0.z; lp3=(unsigned short)run;
            run += c0.w; lp4=(unsigned short)run;
            run += c1.x; lp5=(unsigned short)run;
            run += c1.y; lp6=(unsigned short)run;
            run += c1.z; lp7=(unsigned short)run;
            run += c1.w; tot = run;
            ushort4 a, b;
            a.x=lp0; a.y=lp1; a.z=lp2; a.w=lp3;
            b.x=lp4; b.y=lp5; b.z=lp6; b.w=lp7;
            *(ushort4*)&lsp[(size_t)node*8]   = a;
            *(ushort4*)&lsp[(size_t)node*8+4] = b;
        }
        t[j] = tot;
    }
    int v1=t[0], v2=t[0]+t[1], v3=v2+t[2];
    int s = v3+t[3];
    sd[tid]=s; __syncthreads();
    for (int off=1; off<256; off<<=1){
        int tt = (tid>=off)? sd[tid-off] : 0;
        __syncthreads();
        sd[tid] += tt;
        __syncthreads();
    }
    int excl = sd[tid] - s;
    if (base+0<n) offs[base+0]=excl;
    if (base+1<n) offs[base+1]=excl+v1;
    if (base+2<n) offs[base+2]=excl+v2;
    if (base+3<n) offs[base+3]=excl+v3;
    if (tid==255) bsum[blockIdx.x]=sd[255];
}

// block-sum prefix fused; writes absolute shard bases
__global__ void scan3_kernel(int* __restrict__ offs, int* __restrict__ sbase,
                             const unsigned short* __restrict__ lsp,
                             const int* __restrict__ bsum, int n, int E, int nb){
    __shared__ int sexcl;
    int tid = threadIdx.x;
    if (tid < 64){
        int v = (tid < nb) ? bsum[tid] : 0;
        int orig = v;
        #pragma unroll
        for (int off=1; off<64; off<<=1){
            int t = __shfl_up(v, off);
            if (tid >= off) v += t;
        }
        int g = blockIdx.x >> 2;
        if (tid == g) sexcl = v - orig;
    }
    __syncthreads();
    int i = blockIdx.x*256 + tid;
    if (i<n){
        int o = offs[i] + sexcl;
        offs[i] = o;
        ushort4 a = *(const ushort4*)&lsp[(size_t)i*8];
        ushort4 b = *(const ushort4*)&lsp[(size_t)i*8+4];
        int4 s0, s1;
        s0.x=o+a.x; s0.y=o+a.y; s0.z=o+a.z; s0.w=o+a.w;
        s1.x=o+b.x; s1.y=o+b.y; s1.z=o+b.z; s1.w=o+b.w;
        *(int4*)&sbase[(size_t)i*8]   = s0;
        *(int4*)&sbase[(size_t)i*8+4] = s1;
    }
    if (i==0) offs[n]=E;
}

// atomic-free scatter: pos = sbase[d][shard] + saved slot
__global__ void scatter_kernel(const int* __restrict__ src, const int* __restrict__ dst,
                               const float* __restrict__ w,
                               const int* __restrict__ sbase,
                               const unsigned short* __restrict__ slot,
                               unsigned int* __restrict__ edges, int E){
    int e = blockIdx.x*256+threadIdx.x;
    if (e<E){
        int d = dst[e];
        int pos = sbase[d*8 + (e & 7)] + (int)slot[e];
        edges[pos] = ((unsigned int)src[e] << 16) | (unsigned int)f2h(w[e]);
    }
}

// ---- GEMM1: X[M,512]fp32 @ W1t -> S1 bf16 [M,128] ----
// BK=128 phases: 4 stage/compute phases, 8 barriers total. A prefetched across
// the phase barrier in registers (8 indep float4 HBM loads in flight).
__global__ __launch_bounds__(256) void gemm1_mfma(const float* __restrict__ X,
                                                  const unsigned short* __restrict__ W1t,
                                                  unsigned short* __restrict__ S1, int M){
    __shared__ unsigned short sB[128*136];  // [n][136]: 272B stride -> 2-way bank alias (free)
    int tid = threadIdx.x;
    int wave = tid >> 6, lane = tid & 63;
    int quad = lane >> 4, l16 = lane & 15;
    int row0 = blockIdx.x * 64;
    int myrow = row0 + wave*16 + l16;
    int arow = min(myrow, M-1);
    const float* xrow = X + (size_t)arow * F0;

    f32x4 acc[8];
    #pragma unroll
    for (int c=0;c<8;c++) acc[c] = (f32x4){0.f,0.f,0.f,0.f};

    // prologue: A for phase 0 (4 k-steps x 2 float4)
    float4 aq[4][2];
    #pragma unroll
    for (int s=0;s<4;s++){
        aq[s][0] = *(const float4*)(xrow + s*32 + quad*8);
        aq[s][1] = *(const float4*)(xrow + s*32 + quad*8 + 4);
    }

    for (int p = 0; p < 4; p++){
        __syncthreads();   // prior phase's LDS reads done
        // stage B phase p: 2048 float4s across 256 threads (8 iters)
        #pragma unroll
        for (int i=0;i<8;i++){
            int idx = tid + i*256;          // 0..2047
            int nn = idx >> 4, c8 = idx & 15;
            *(float4*)&sB[nn*136 + c8*8] =
                *(const float4*)&W1t[(size_t)nn*F0 + p*128 + c8*8];
        }
        __syncthreads();
        // prefetch next phase's A (issues before MFMA block, lands during it)
        float4 nq[4][2];
        if (p < 3){
            const float* nx = xrow + (p+1)*128;
            #pragma unroll
            for (int s=0;s<4;s++){
                nq[s][0] = *(const float4*)(nx + s*32 + quad*8);
                nq[s][1] = *(const float4*)(nx + s*32 + quad*8 + 4);
            }
        }
        #pragma unroll
        for (int s=0;s<4;s++){
            bf16x8 af = pack8(aq[s][0], aq[s][1]);
            #pragma unroll
            for (int c=0;c<8;c++){
                bf16x8 b = *(bf16x8*)&sB[(c*16 + l16)*136 + s*32 + quad*8];
                acc[c] = __builtin_amdgcn_mfma_f32_16x16x32_bf16(af, b, acc[c], 0, 0, 0);
            }
        }
        if (p < 3){
            #pragma unroll
            for (int s=0;s<4;s++){ aq[s][0]=nq[s][0]; aq[s][1]=nq[s][1]; }
        }
    }
    // C/D: col = c*16 + l16, row = quad*4 + r
    #pragma unroll
    for (int c=0;c<8;c++){
        #pragma unroll
        for (int r=0;r<4;r++){
            int grow = row0 + wave*16 + quad*4 + r;
            if (grow < M) S1[(size_t)grow*F1 + c*16 + l16] = f2b_fast(acc[c][r]);
        }
    }
}

// ---- agg1: H = relu(A@S1 + b1) bf16, F=128 (unchanged from R6) ----
__global__ void agg1_kernel(const unsigned short* __restrict__ S1, const int* __restrict__ offs,
                            const unsigned int* __restrict__ edges,
                            const float* __restrict__ b1, unsigned short* __restrict__ H, int n){
    int node = blockIdx.x*4 + (threadIdx.x >> 6);   // one wave per node
    int lane = threadIdx.x & 63;
    if (node >= n) return;
    int half = lane >> 5, fl = lane & 31;
    int e0 = offs[node], e1 = offs[node+1];
    double a0=0.0, a1=0.0, a2=0.0, a3=0.0;
    int e = e0;
    for (; e+8 <= e1; e += 8){
        unsigned int rA = edges[e   + half];
        unsigned int rB = edges[e+2 + half];
        unsigned int rC = edges[e+4 + half];
        unsigned int rD = edges[e+6 + half];
        ushort4 vA = *(const ushort4*)&S1[((size_t)(rA>>16))*F1 + fl*4];
        ushort4 vB = *(const ushort4*)&S1[((size_t)(rB>>16))*F1 + fl*4];
        ushort4 vC = *(const ushort4*)&S1[((size_t)(rC>>16))*F1 + fl*4];
        ushort4 vD = *(const ushort4*)&S1[((size_t)(rD>>16))*F1 + fl*4];
        double wA = h2f((unsigned short)rA), wB = h2f((unsigned short)rB);
        double wC = h2f((unsigned short)rC), wD = h2f((unsigned short)rD);
        a0 += wA*b2f(vA.x) + wB*b2f(vB.x) + wC*b2f(vC.x) + wD*b2f(vD.x);
        a1 += wA*b2f(vA.y) + wB*b2f(vB.y) + wC*b2f(vC.y) + wD*b2f(vD.y);
        a2 += wA*b2f(vA.z) + wB*b2f(vB.z) + wC*b2f(vC.z) + wD*b2f(vD.z);
        a3 += wA*b2f(vA.w) + wB*b2f(vB.w) + wC*b2f(vC.w) + wD*b2f(vD.w);
    }
    for (; e < e1; e += 2){
        int ee = e + half;
        if (ee < e1){
            unsigned int r = edges[ee];
            ushort4 v = *(const ushort4*)&S1[((size_t)(r>>16))*F1 + fl*4];
            double w = h2f((unsigned short)r);
            a0 += w*b2f(v.x); a1 += w*b2f(v.y); a2 += w*b2f(v.z); a3 += w*b2f(v.w);
        }
    }
    a0 += __shfl_down(a0, 32);
    a1 += __shfl_down(a1, 32);
    a2 += __shfl_down(a2, 32);
    a3 += __shfl_down(a3, 32);
    if (lane < 32){
        float4 bb = *(const float4*)&b1[fl*4];
        float o0 = (float)(a0 + (double)bb.x);
        float o1 = (float)(a1 + (double)bb.y);
        float o2 = (float)(a2 + (double)bb.z);
        float o3 = (float)(a3 + (double)bb.w);
        o0 = o0>0.f?o0:0.f; o1 = o1>0.f?o1:0.f;
        o2 = o2>0.f?o2:0.f; o3 = o3>0.f?o3:0.f;
        union { ushort4 v; unsigned int d[2]; } o;
        o.d[0] = pack2(o0, o1);
        o.d[1] = pack2(o2, o3);
        *(ushort4*)&H[(size_t)node*F1 + fl*4] = o.v;
    }
}

// ---- GEMM2: H bf16 [M,128] @ W2t -> S2 bf16 [M,48] (unchanged) ----
__global__ __launch_bounds__(256) void gemm2_mfma(const unsigned short* __restrict__ H,
                                                  const unsigned short* __restrict__ W2t,
                                                  unsigned short* __restrict__ S2, int M){
    __shared__ unsigned short sB[48][136];
    int tid = threadIdx.x;
    int wave = tid >> 6, lane = tid & 63;
    int quad = lane >> 4, l16 = lane & 15;
    for (int i = tid; i < 48*16; i += 256){
        int nn = i >> 4, p = i & 15;
        *(float4*)&sB[nn][p*8] = *(const float4*)&W2t[(size_t)nn*F1 + p*8];
    }
    int row0 = blockIdx.x * 64;
    int myrow = row0 + wave*16 + l16;
    int arow = min(myrow, M-1);
    const unsigned short* hrow = H + (size_t)arow * F1;
    bf16x8 a[4];
    #pragma unroll
    for (int ks=0; ks<4; ks++) a[ks] = *(const bf16x8*)(hrow + ks*32 + quad*8);
    __syncthreads();
    f32x4 acc[3];
    #pragma unroll
    for (int c=0;c<3;c++) acc[c] = (f32x4){0.f,0.f,0.f,0.f};
    #pragma unroll
    for (int ks=0; ks<4; ks++){
        #pragma unroll
        for (int c=0;c<3;c++){
            bf16x8 b = *(bf16x8*)&sB[c*16 + l16][ks*32 + quad*8];
            acc[c] = __builtin_amdgcn_mfma_f32_16x16x32_bf16(a[ks], b, acc[c], 0, 0, 0);
        }
    }
    #pragma unroll
    for (int c=0;c<3;c++){
        #pragma unroll
        for (int r=0;r<4;r++){
            int grow = row0 + wave*16 + quad*4 + r;
            if (grow < M) S2[(size_t)grow*F2P + c*16 + l16] = f2b_fast(acc[c][r]);
        }
    }
}

// ---- agg2: out = A@S2 + b2, F=40 (unchanged) ----
__global__ void agg2_kernel(const unsigned short* __restrict__ S2, const int* __restrict__ offs,
                            const unsigned int* __restrict__ edges,
                            const float* __restrict__ b2, float* __restrict__ out, int n){
    int node = blockIdx.x*4 + (threadIdx.x >> 6);  // one wave per node
    int lane = threadIdx.x & 63;
    if (node >= n) return;
    int grp = lane >> 4, gl = lane & 15;
    bool act = gl < 10;
    int e0 = offs[node], e1 = offs[node+1];
    double a0=0.0, a1=0.0, a2=0.0, a3=0.0;
    for (int e = e0; e < e1; e += 4){
        int ee = e + grp;
        if (ee < e1 && act){
            unsigned int r = edges[ee];
            ushort4 v = *(const ushort4*)&S2[((size_t)(r>>16))*F2P + gl*4];
            double w = h2f((unsigned short)r);
            a0 += w*b2f(v.x); a1 += w*b2f(v.y); a2 += w*b2f(v.z); a3 += w*b2f(v.w);
        }
    }
    a0 += __shfl_down(a0, 32); a0 += __shfl_down(a0, 16);
    a1 += __shfl_down(a1, 32); a1 += __shfl_down(a1, 16);
    a2 += __shfl_down(a2, 32); a2 += __shfl_down(a2, 16);
    a3 += __shfl_down(a3, 32); a3 += __shfl_down(a3, 16);
    if (lane < 10){
        float4 bb = *(const float4*)&b2[lane*4];
        float4 o;
        o.x = (float)(a0 + (double)bb.x);
        o.y = (float)(a1 + (double)bb.y);
        o.z = (float)(a2 + (double)bb.z);
        o.w = (float)(a3 + (double)bb.w);
        *(float4*)&out[(size_t)node*F2 + lane*4] = o;
    }
}

extern "C" void kernel_launch(void* const* d_in, const int* in_sizes, int n_in,
                              void* d_out, int out_size, void* d_ws, size_t ws_size,
                              hipStream_t stream){
    const float* x    = (const float*)d_in[0];
    const int*   esrc = (const int*)d_in[1];
    const int*   edst = (const int*)d_in[2];
    const float* ew   = (const float*)d_in[3];
    const float* W1   = (const float*)d_in[4];
    const float* b1   = (const float*)d_in[5];
    const float* W2   = (const float*)d_in[6];
    const float* b2   = (const float*)d_in[7];
    float* out = (float*)d_out;
    int N = in_sizes[0] / F0;   // 50000
    int E = in_sizes[1];        // 800000

    char* ws = (char*)d_ws;
    size_t off = 0;
    auto alloc = [&](size_t bytes)->void*{
        void* p = ws + off; off += (bytes + 255) & ~(size_t)255; return p;
    };
    unsigned short* S1 = (unsigned short*)alloc(sizeof(unsigned short)*(size_t)N*F1);  // 12.8 MB
    unsigned short* H  = (unsigned short*)alloc(sizeof(unsigned short)*(size_t)N*F1);  // 12.8 MB
    unsigned short* S2 = (unsigned short*)alloc(sizeof(unsigned short)*(size_t)N*F2P); // 4.8 MB
    unsigned short* W1t = (unsigned short*)alloc(sizeof(unsigned short)*F1*F0);
    unsigned short* W2t = (unsigned short*)alloc(sizeof(unsigned short)*F2P*F1);
    int*   offs  = (int*)alloc(sizeof(int)*(size_t)(N+1));
    int*   cnt8  = (int*)alloc(sizeof(int)*(size_t)N*8);                 // 1.6 MB
    int*   sbase = (int*)alloc(sizeof(int)*(size_t)N*8);                 // 1.6 MB
    unsigned short* lsp  = (unsigned short*)alloc(sizeof(unsigned short)*(size_t)N*8); // 0.8 MB
    unsigned short* slot = (unsigned short*)alloc(sizeof(unsigned short)*(size_t)E);   // 1.6 MB
    unsigned int* edges = (unsigned int*)alloc(sizeof(unsigned int)*(size_t)E);        // 3.2 MB
    int*   bsum  = (int*)alloc(sizeof(int)*64);

    int n8 = N*8;
    // weight prep + cnt8 zero (grid covers both workloads)
    int prep_items = n8 > (F0*F1 + F2P*F1) ? n8 : (F0*F1 + F2P*F1);
    prep_w<<<(prep_items+255)/256,256,0,stream>>>(W1, W2, W1t, W2t, cnt8, n8);

    // CSR build: sharded hist -> scan (emits shard bases) -> atomic-free scatter
    hist_kernel<<<(E+255)/256,256,0,stream>>>(edst, cnt8, slot, E);
    int nb = (N+1023)/1024;     // 49 <= 64
    scan1_kernel<<<nb,256,0,stream>>>(cnt8, offs, lsp, bsum, N);
    scan3_kernel<<<(N+255)/256,256,0,stream>>>(offs, sbase, lsp, bsum, N, E, nb);
    scatter_kernel<<<(E+255)/256,256,0,stream>>>(esrc, edst, ew, sbase, slot, edges, E);

    // layer 1
    gemm1_mfma<<<(N+63)/64,256,0,stream>>>(x, W1t, S1, N);
    agg1_kernel<<<(N+3)/4,256,0,stream>>>(S1, offs, edges, b1, H, N);
    // layer 2
    gemm2_mfma<<<(N+63)/64,256,0,stream>>>(H, W2t, S2, N);
    agg2_kernel<<<(N+3)/4,256,0,stream>>>(S2, offs, edges, b2, out, N);
}